// Round 6
// baseline (260.312 us; speedup 1.0000x reference)
//
#include <hip/hip_runtime.h>
#include <hip/hip_bf16.h>

#define NN 50000
#define NE 500000
#define HD 128
#define CAP 128
#define PREP_B 24
#define ZCUR_B ((NN + 255) / 256)          // 196
#define ZAGGR_B 6250
#define FILLB_B ((NE + 255) / 256)         // 1954
#define XCONV_B 3125
#define K2_B (FILLB_B + XCONV_B)           // 5079

typedef __bf16 bf16;
typedef __attribute__((ext_vector_type(8))) __bf16 bf16x8;
typedef __attribute__((ext_vector_type(4))) float floatx4;

__device__ inline float u2f(unsigned int lo16) {
    union { unsigned int i; float f; } c; c.i = lo16 << 16; return c.f;
}

__device__ inline bf16x8 cvt8(floatx4 a, floatx4 b) {
    bf16x8 r;
#pragma unroll
    for (int j = 0; j < 4; j++) { r[j] = (bf16)a[j]; r[j + 4] = (bf16)b[j]; }
    return r;
}

__device__ inline void split8(const floatx4 f0, const floatx4 f1, bf16x8& hi, bf16x8& lo) {
#pragma unroll
    for (int j = 0; j < 4; j++) {
        float a = f0[j]; bf16 h = (bf16)a; hi[j] = h; lo[j] = (bf16)(a - (float)h);
        float b = f1[j]; bf16 g = (bf16)b; hi[j + 4] = g; lo[j + 4] = (bf16)(b - (float)g);
    }
}

__device__ inline bf16x8 zero8() {
    bf16x8 v;
#pragma unroll
    for (int j = 0; j < 8; j++) v[j] = (bf16)0.f;
    return v;
}

// accumulate 8 bf16 (one uint4) into two floatx4 (feats 0..3 -> f0, 4..7 -> f1)
__device__ inline void addrow(floatx4& f0, floatx4& f1, const uint4 v) {
    f0[0] += u2f(v.x & 0xffff); f0[1] += u2f(v.x >> 16);
    f0[2] += u2f(v.y & 0xffff); f0[3] += u2f(v.y >> 16);
    f1[0] += u2f(v.z & 0xffff); f1[1] += u2f(v.z >> 16);
    f1[2] += u2f(v.w & 0xffff); f1[3] += u2f(v.w >> 16);
}

// issue 16 loads (4 edges x 4 chunks) into named uint4 regs v00..v33
#define GLOAD16(v, S) do { \
    const uint4* p0_ = (const uint4*)(xb + (size_t)(S).x * HD + q8); \
    const uint4* p1_ = (const uint4*)(xb + (size_t)(S).y * HD + q8); \
    const uint4* p2_ = (const uint4*)(xb + (size_t)(S).z * HD + q8); \
    const uint4* p3_ = (const uint4*)(xb + (size_t)(S).w * HD + q8); \
    v##00 = p0_[0]; v##01 = p0_[4]; v##02 = p0_[8]; v##03 = p0_[12]; \
    v##10 = p1_[0]; v##11 = p1_[4]; v##12 = p1_[8]; v##13 = p1_[12]; \
    v##20 = p2_[0]; v##21 = p2_[4]; v##22 = p2_[8]; v##23 = p2_[12]; \
    v##30 = p3_[0]; v##31 = p3_[4]; v##32 = p3_[8]; v##33 = p3_[12]; \
} while (0)

#define GUNPACK(v) do { \
    addrow(ag0[0], ag1[0], v##00); addrow(ag0[1], ag1[1], v##01); \
    addrow(ag0[2], ag1[2], v##02); addrow(ag0[3], ag1[3], v##03); \
    addrow(ag0[0], ag1[0], v##10); addrow(ag0[1], ag1[1], v##11); \
    addrow(ag0[2], ag1[2], v##12); addrow(ag0[3], ag1[3], v##13); \
    addrow(ag0[0], ag1[0], v##20); addrow(ag0[1], ag1[1], v##21); \
    addrow(ag0[2], ag1[2], v##22); addrow(ag0[3], ag1[3], v##23); \
    addrow(ag0[0], ag1[0], v##30); addrow(ag0[1], ag1[1], v##31); \
    addrow(ag0[2], ag1[2], v##32); addrow(ag0[3], ag1[3], v##33); \
} while (0)

// ===== K1: weights->bf16 (24) | zero cur + ovf_cnt (196) | [tier0 only: zero aggr (6250)] =====
__global__ __launch_bounds__(256) void k_setup1(
    const float* __restrict__ wl, const float* __restrict__ w0, const float* __restrict__ w1,
    const float* __restrict__ bl, const float* __restrict__ b0, const float* __restrict__ b1,
    const float* __restrict__ ow, const float* __restrict__ ob,
    bf16* __restrict__ wlb, bf16* __restrict__ w01b, bf16* __restrict__ owb,
    float* __restrict__ bias1, float* __restrict__ bias2,
    float* __restrict__ aggr, int* __restrict__ cur, int* __restrict__ ovf_cnt, int tier)
{
    const int b = blockIdx.x, tid = threadIdx.x;
    if (b < PREP_B) {
        int g = b * 256 + tid;
        int m = g >> 11, off = (g & 2047) << 3;
        if (m == 0) {
            const floatx4 a = *(const floatx4*)(wl + off);
            const floatx4 c = *(const floatx4*)(wl + off + 4);
            *(bf16x8*)(wlb + off) = cvt8(a, c);
        } else if (m == 1) {
            floatx4 a = *(const floatx4*)(w0 + off);
            floatx4 c = *(const floatx4*)(w0 + off + 4);
            const floatx4 d = *(const floatx4*)(w1 + off);
            const floatx4 e = *(const floatx4*)(w1 + off + 4);
#pragma unroll
            for (int j = 0; j < 4; j++) { a[j] += d[j]; c[j] += e[j]; }
            *(bf16x8*)(w01b + off) = cvt8(a, c);
        } else {
            const floatx4 a = *(const floatx4*)(ow + off);
            const floatx4 c = *(const floatx4*)(ow + off + 4);
            *(bf16x8*)(owb + off) = cvt8(a, c);
        }
        if (g < 128) bias1[g] = bl[g] + b0[g] + b1[g];
        else if (g < 256) bias2[g - 128] = ob[g - 128];
    } else if (b < PREP_B + ZCUR_B) {
        if (tier >= 1) {
            int i = (b - PREP_B) * 256 + tid;
            if (i < NN) cur[i] = 0;
            if (b == PREP_B && tid == 0) *ovf_cnt = 0;
        }
    } else {
        // only present in tier-0 grid: zero aggr for the atomic-scatter fallback
        int i = (b - PREP_B - ZCUR_B) * 256 + tid;
        floatx4 z = {0.f, 0.f, 0.f, 0.f};
        ((floatx4*)aggr)[i] = z;
    }
}

// ===== K2: bucket append (1954) | x->bf16 (3125) — independent, co-scheduled =====
__global__ __launch_bounds__(256) void k_setup2(
    const int* __restrict__ edge, const float* __restrict__ x,
    int* __restrict__ cur, int* __restrict__ bucket,
    int* __restrict__ ovf_cnt, int* __restrict__ ovf,
    bf16* __restrict__ xb)
{
    const int b = blockIdx.x, tid = threadIdx.x;
    if (b < FILLB_B) {
        int e = b * 256 + tid;
        if (e >= NE) return;
        int dst = edge[e];
        int src = edge[NE + e];
        int pos = atomicAdd(&cur[dst], 1);
        if (pos < CAP) {
            bucket[dst * CAP + pos] = src;
        } else {   // statistically never — correctness valve via overflow list
            int oi = atomicAdd(ovf_cnt, 1);
            ovf[2 * oi] = dst;
            ovf[2 * oi + 1] = src;
        }
    } else {
        int off = ((b - FILLB_B) * 256 + tid) << 3;
        const floatx4 a = *(const floatx4*)(x + off);
        const floatx4 c = *(const floatx4*)(x + off + 4);
        *(bf16x8*)(xb + off) = cvt8(a, c);
    }
}

// ======== fallback atomic scatter (tier-0, proven; aggr pre-zeroed by K1) ========
__global__ __launch_bounds__(256) void k_scatter(const float* __restrict__ x,
                                                 const int* __restrict__ edge,
                                                 float* __restrict__ aggr) {
    int tid = blockIdx.x * 256 + threadIdx.x;
    int e = tid >> 5;
    int c = (tid & 31) << 2;
    int dst = edge[e];
    int src = edge[NE + e];
    const floatx4 v = *(const floatx4*)(x + src * HD + c);
    float* ap = aggr + dst * HD + c;
    unsafeAtomicAdd(ap + 0, v[0]);
    unsafeAtomicAdd(ap + 1, v[1]);
    unsafeAtomicAdd(ap + 2, v[2]);
    unsafeAtomicAdd(ap + 3, v[3]);
}

// ======== fused gather-aggregate + GEMM1 + GEMM2 with LDS overlay (~70.7 KB -> 2 blocks/CU) ====
// LDS caps residency at 2 blocks/CU = 2 waves/SIMD, so the VGPR budget is 256/wave: the gather
// runs a 2-deep software pipeline of 4-edge groups (32 uint4 loads in flight per lane).
// __launch_bounds__(256,2) = exactly the LDS-forced occupancy; lets the allocator use ~200 VGPRs.
__global__ __launch_bounds__(256, 2) void k_fused(
    const float* __restrict__ aggr, const float* __restrict__ x, const bf16* __restrict__ xb,
    int tier,
    const int* __restrict__ cur, const int* __restrict__ bucket,
    const int* __restrict__ ovf_cnt, const int* __restrict__ ovf,
    const bf16* __restrict__ wlb, const bf16* __restrict__ w01b, const bf16* __restrict__ owb,
    const float* __restrict__ bias1, const float* __restrict__ bias2,
    float* __restrict__ out)
{
    __shared__ bf16 sA[128 * 136];        // wl, then ow
    __shared__ bf16 sB[128 * 136];        // w01, then tp (h transpose)
    __shared__ float b1_s[128], b2_s[128];
    float* tp = (float*)sB;               // [4][16][132]
    const int tid = threadIdx.x;

#pragma unroll
    for (int it = 0; it < 8; it++) {
        int i = tid + it * 256;
        int r = i >> 4;
        int o = (i & 15) << 3;
        *(bf16x8*)(sA + r * 136 + o) = *(const bf16x8*)(wlb  + r * 128 + o);
        *(bf16x8*)(sB + r * 136 + o) = *(const bf16x8*)(w01b + r * 128 + o);
    }
    if (tid < 128) { b1_s[tid] = bias1[tid]; b2_s[tid] = bias2[tid]; }
    // staging sync deferred to after the register gather (gather touches no LDS),
    // so staging stores drain while the gather runs.

    const int lane = tid & 63;
    const int wv   = tid >> 6;
    const int ln   = lane & 15;
    const int quad = lane >> 4;
    const int row0 = blockIdx.x * 64 + wv * 16;
    const int arow = row0 + ln;
    const bool aok = arow < NN;
    const int q8   = quad * 8;

    floatx4 ag0[4] = {};   // ag0[kc] = aggregated feats kc*32+q8 .. +3
    floatx4 ag1[4] = {};   // ag1[kc] = aggregated feats kc*32+q8+4 .. +7

    // preload this row's x-features (GEMM1 a_x operand) so the loads ride under the gather
    bf16x8 ax[4] = {zero8(), zero8(), zero8(), zero8()};
    if (tier && aok) {
#pragma unroll
        for (int kc = 0; kc < 4; kc++)
            ax[kc] = *(const bf16x8*)(xb + (size_t)arow * HD + kc * 32 + q8);
    }

    if (tier) {
        int deg = 0, n = 0;
        if (aok) { deg = cur[arow]; n = (deg < CAP) ? deg : CAP; }
        const int* bk = bucket + (size_t)arow * CAP;
        int t = 0;
        uint4 a00, a01, a02, a03, a10, a11, a12, a13,
              a20, a21, a22, a23, a30, a31, a32, a33;
        uint4 b00, b01, b02, b03, b10, b11, b12, b13,
              b20, b21, b22, b23, b30, b31, b32, b33;
        if (t + 3 < n) {
            int4 si = *(const int4*)(bk);              // bucket rows 512B-aligned
            GLOAD16(a, si);                            // group A in flight
            t = 4;
            while (t + 3 < n) {
                const int4 sj = *(const int4*)(bk + t);
                GLOAD16(b, sj);                        // group B in flight (32 total)
                t += 4;
                GUNPACK(a);                            // consume A under B's latency
                if (t + 3 < n) {
                    si = *(const int4*)(bk + t);
                    GLOAD16(a, si);                    // refill A (32 in flight again)
                    t += 4;
                    GUNPACK(b);
                } else {
                    GUNPACK(b);
                    goto gdone;
                }
            }
            GUNPACK(a);                                // loop exited with only A pending
gdone:      ;
        }
        for (; t < n; t++) {
            const bf16* r0 = xb + (size_t)bk[t] * HD + q8;
            const uint4 e0 = *(const uint4*)(r0);
            const uint4 e1 = *(const uint4*)(r0 + 32);
            const uint4 e2 = *(const uint4*)(r0 + 64);
            const uint4 e3 = *(const uint4*)(r0 + 96);
            addrow(ag0[0], ag1[0], e0); addrow(ag0[1], ag1[1], e1);
            addrow(ag0[2], ag1[2], e2); addrow(ag0[3], ag1[3], e3);
        }
        if (deg > CAP) {                  // never fires for the bench inputs
            const int m = *ovf_cnt;
            for (int i = 0; i < m; i++) {
                if (ovf[2 * i] == arow) {
                    const bf16* r0 = xb + (size_t)ovf[2 * i + 1] * HD + q8;
                    const uint4 e0 = *(const uint4*)(r0);
                    const uint4 e1 = *(const uint4*)(r0 + 32);
                    const uint4 e2 = *(const uint4*)(r0 + 64);
                    const uint4 e3 = *(const uint4*)(r0 + 96);
                    addrow(ag0[0], ag1[0], e0); addrow(ag0[1], ag1[1], e1);
                    addrow(ag0[2], ag1[2], e2); addrow(ag0[3], ag1[3], e3);
                }
            }
        }
    } else if (aok) {                     // tier-0: aggr came from the atomic scatter
#pragma unroll
        for (int kc = 0; kc < 4; kc++) {
            ag0[kc] = *(const floatx4*)(aggr + (size_t)arow * HD + kc * 32 + q8);
            ag1[kc] = *(const floatx4*)(aggr + (size_t)arow * HD + kc * 32 + q8 + 4);
        }
    }

    __syncthreads();                      // weights staged; gather results live in regs

    floatx4 acc[8] = {};

    // ---- GEMM1 ----
#pragma unroll
    for (int kc = 0; kc < 4; kc++) {
        const int k0 = kc * 32 + q8;
        bf16x8 a_hi, a_lo;
        split8(ag0[kc], ag1[kc], a_hi, a_lo);
        bf16x8 a_x = ax[kc];
        if (!tier && aok) {
            const floatx4 g0 = *(const floatx4*)(x + (size_t)arow * HD + k0);
            const floatx4 g1 = *(const floatx4*)(x + (size_t)arow * HD + k0 + 4);
            a_x = cvt8(g0, g1);
        }
#pragma unroll
        for (int nc = 0; nc < 8; nc++) {
            const bf16x8 bw  = *(const bf16x8*)(sA + (nc * 16 + ln) * 136 + k0);
            const bf16x8 bw2 = *(const bf16x8*)(sB + (nc * 16 + ln) * 136 + k0);
            acc[nc] = __builtin_amdgcn_mfma_f32_16x16x32_bf16(a_hi, bw,  acc[nc], 0, 0, 0);
            acc[nc] = __builtin_amdgcn_mfma_f32_16x16x32_bf16(a_lo, bw,  acc[nc], 0, 0, 0);
            acc[nc] = __builtin_amdgcn_mfma_f32_16x16x32_bf16(a_x,  bw2, acc[nc], 0, 0, 0);
        }
    }
    __syncthreads();

    // ---- overlay: restage ow into sA; park relu(h) into tp (over sB) ----
#pragma unroll
    for (int it = 0; it < 8; it++) {
        int i = tid + it * 256;
        int r = i >> 4;
        int o = (i & 15) << 3;
        *(bf16x8*)(sA + r * 136 + o) = *(const bf16x8*)(owb + r * 128 + o);
    }
#pragma unroll
    for (int nc = 0; nc < 8; nc++) {
        const int col = nc * 16 + ln;
        const float bv = b1_s[col];
#pragma unroll
        for (int r = 0; r < 4; r++) {
            float v = acc[nc][r] + bv;
            tp[wv * 2112 + (quad * 4 + r) * 132 + col] = (v > 0.f ? v : 0.f);
        }
        acc[nc][0] = acc[nc][1] = acc[nc][2] = acc[nc][3] = 0.f;
    }
    __syncthreads();

    // ---- GEMM2 ----
#pragma unroll
    for (int kc = 0; kc < 4; kc++) {
        const int k0 = kc * 32 + q8;
        const floatx4 f0 = *(const floatx4*)(tp + wv * 2112 + ln * 132 + k0);
        const floatx4 f1 = *(const floatx4*)(tp + wv * 2112 + ln * 132 + k0 + 4);
        bf16x8 a_hi, a_lo;
        split8(f0, f1, a_hi, a_lo);
#pragma unroll
        for (int nc = 0; nc < 8; nc++) {
            const bf16x8 bw = *(const bf16x8*)(sA + (nc * 16 + ln) * 136 + k0);
            acc[nc] = __builtin_amdgcn_mfma_f32_16x16x32_bf16(a_hi, bw, acc[nc], 0, 0, 0);
            acc[nc] = __builtin_amdgcn_mfma_f32_16x16x32_bf16(a_lo, bw, acc[nc], 0, 0, 0);
        }
    }

#pragma unroll
    for (int nc = 0; nc < 8; nc++) {
        const int col = nc * 16 + ln;
        const float bv = bias2 == nullptr ? 0.f : b2_s[col];
#pragma unroll
        for (int r = 0; r < 4; r++) {
            const int row = row0 + quad * 4 + r;
            if (row < NN) out[row * 128 + col] = acc[nc][r] + bv;
        }
    }
}

extern "C" void kernel_launch(void* const* d_in, const int* in_sizes, int n_in,
                              void* d_out, int out_size, void* d_ws, size_t ws_size,
                              hipStream_t stream) {
    const float* x_a     = (const float*)d_in[0];
    const int*   edge_ba = (const int*)d_in[3];
    const float* c1_w0_w = (const float*)d_in[10];
    const float* c1_w0_b = (const float*)d_in[11];
    const float* c1_wl_w = (const float*)d_in[12];
    const float* c1_wl_b = (const float*)d_in[13];
    const float* c1_w1_w = (const float*)d_in[14];
    const float* c1_w1_b = (const float*)d_in[15];
    const float* out_w   = (const float*)d_in[16];
    const float* out_b   = (const float*)d_in[17];

    char* p = (char*)d_ws;
    float* aggr  = (float*)p;   p += (size_t)NN * HD * 4;     // 25.6 MB (tier-0 fallback only)
    bf16*  wlb   = (bf16*)p;    p += 32768;
    bf16*  w01b  = (bf16*)p;    p += 32768;
    bf16*  owb   = (bf16*)p;    p += 32768;
    float* bias1 = (float*)p;   p += 512;
    float* bias2 = (float*)p;   p += 512;
    const size_t WS_FALL = (size_t)(p - (char*)d_ws);         // ~25.7 MB
    int*   cur    = (int*)p;    p += 200704;                  // NN ints (padded)
    int*   bucket = (int*)p;    p += (size_t)NN * CAP * 4;    // 25.6 MB
    bf16*  xb     = (bf16*)p;   p += (size_t)NN * HD * 2;     // 12.8 MB
    int*   ovf_cnt= (int*)p;    p += 256;
    int*   ovf    = (int*)p;    p += (size_t)NE * 2 * 4;      // 4 MB overflow (dst,src) pairs
    const size_t WS_BUCKET = (size_t)(p - (char*)d_ws);       // ~68.5 MB (ws = 256 MiB)
    (void)WS_FALL;

    const int tier = (ws_size >= WS_BUCKET) ? 1 : 0;

    const int k1_grid = tier ? (PREP_B + ZCUR_B) : (PREP_B + ZCUR_B + ZAGGR_B);
    k_setup1<<<k1_grid, 256, 0, stream>>>(c1_wl_w, c1_w0_w, c1_w1_w,
                                          c1_wl_b, c1_w0_b, c1_w1_b,
                                          out_w, out_b,
                                          wlb, w01b, owb, bias1, bias2,
                                          aggr, cur, ovf_cnt, tier);

    if (tier) {
        k_setup2<<<K2_B, 256, 0, stream>>>(edge_ba, x_a, cur, bucket, ovf_cnt, ovf, xb);
    } else {
        k_scatter<<<NE * 32 / 256, 256, 0, stream>>>(x_a, edge_ba, aggr);
    }

    k_fused<<<(NN + 63) / 64, 256, 0, stream>>>(aggr, x_a, xb, tier,
                                                cur, bucket, ovf_cnt, ovf,
                                                wlb, w01b, owb, bias1, bias2,
                                                (float*)d_out);
}

// Round 7
// 208.962 us; speedup vs baseline: 1.2457x; 1.2457x over previous
//
#include <hip/hip_runtime.h>
#include <hip/hip_bf16.h>

#define NN 50000
#define NE 500000
#define HD 128
#define CAP 128
#define PREP_B 24
#define ZCUR_B ((NN + 255) / 256)          // 196
#define ZAGGR_B 6250
#define FILLB_B ((NE + 255) / 256)         // 1954
#define XCONV_B 3125
#define K2_B (FILLB_B + XCONV_B)           // 5079

typedef __bf16 bf16;
typedef __attribute__((ext_vector_type(8))) __bf16 bf16x8;
typedef __attribute__((ext_vector_type(4))) float floatx4;

__device__ inline float u2f(unsigned int lo16) {
    union { unsigned int i; float f; } c; c.i = lo16 << 16; return c.f;
}

__device__ inline bf16x8 cvt8(floatx4 a, floatx4 b) {
    bf16x8 r;
#pragma unroll
    for (int j = 0; j < 4; j++) { r[j] = (bf16)a[j]; r[j + 4] = (bf16)b[j]; }
    return r;
}

__device__ inline void split8(const floatx4 f0, const floatx4 f1, bf16x8& hi, bf16x8& lo) {
#pragma unroll
    for (int j = 0; j < 4; j++) {
        float a = f0[j]; bf16 h = (bf16)a; hi[j] = h; lo[j] = (bf16)(a - (float)h);
        float b = f1[j]; bf16 g = (bf16)b; hi[j + 4] = g; lo[j + 4] = (bf16)(b - (float)g);
    }
}

__device__ inline bf16x8 zero8() {
    bf16x8 v;
#pragma unroll
    for (int j = 0; j < 8; j++) v[j] = (bf16)0.f;
    return v;
}

// accumulate 8 bf16 (one uint4) into two floatx4 (feats 0..3 -> f0, 4..7 -> f1)
__device__ inline void addrow(floatx4& f0, floatx4& f1, const uint4 v) {
    f0[0] += u2f(v.x & 0xffff); f0[1] += u2f(v.x >> 16);
    f0[2] += u2f(v.y & 0xffff); f0[3] += u2f(v.y >> 16);
    f1[0] += u2f(v.z & 0xffff); f1[1] += u2f(v.z >> 16);
    f1[2] += u2f(v.w & 0xffff); f1[3] += u2f(v.w >> 16);
}

// issue 16 loads (4 edges x 4 chunks) into named uint4 regs v00..v33
#define GLOAD16(v, S) do { \
    const uint4* p0_ = (const uint4*)(xb + (size_t)(S).x * HD + q8); \
    const uint4* p1_ = (const uint4*)(xb + (size_t)(S).y * HD + q8); \
    const uint4* p2_ = (const uint4*)(xb + (size_t)(S).z * HD + q8); \
    const uint4* p3_ = (const uint4*)(xb + (size_t)(S).w * HD + q8); \
    v##00 = p0_[0]; v##01 = p0_[4]; v##02 = p0_[8]; v##03 = p0_[12]; \
    v##10 = p1_[0]; v##11 = p1_[4]; v##12 = p1_[8]; v##13 = p1_[12]; \
    v##20 = p2_[0]; v##21 = p2_[4]; v##22 = p2_[8]; v##23 = p2_[12]; \
    v##30 = p3_[0]; v##31 = p3_[4]; v##32 = p3_[8]; v##33 = p3_[12]; \
} while (0)

#define GUNPACK(v) do { \
    addrow(ag0[0], ag1[0], v##00); addrow(ag0[1], ag1[1], v##01); \
    addrow(ag0[2], ag1[2], v##02); addrow(ag0[3], ag1[3], v##03); \
    addrow(ag0[0], ag1[0], v##10); addrow(ag0[1], ag1[1], v##11); \
    addrow(ag0[2], ag1[2], v##12); addrow(ag0[3], ag1[3], v##13); \
    addrow(ag0[0], ag1[0], v##20); addrow(ag0[1], ag1[1], v##21); \
    addrow(ag0[2], ag1[2], v##22); addrow(ag0[3], ag1[3], v##23); \
    addrow(ag0[0], ag1[0], v##30); addrow(ag0[1], ag1[1], v##31); \
    addrow(ag0[2], ag1[2], v##32); addrow(ag0[3], ag1[3], v##33); \
} while (0)

// ===== K1: weights->bf16 (24) | zero cur + ovf_cnt (196) | [tier0 only: zero aggr (6250)] =====
__global__ __launch_bounds__(256) void k_setup1(
    const float* __restrict__ wl, const float* __restrict__ w0, const float* __restrict__ w1,
    const float* __restrict__ bl, const float* __restrict__ b0, const float* __restrict__ b1,
    const float* __restrict__ ow, const float* __restrict__ ob,
    bf16* __restrict__ wlb, bf16* __restrict__ w01b, bf16* __restrict__ owb,
    float* __restrict__ bias1, float* __restrict__ bias2,
    float* __restrict__ aggr, int* __restrict__ cur, int* __restrict__ ovf_cnt, int tier)
{
    const int b = blockIdx.x, tid = threadIdx.x;
    if (b < PREP_B) {
        int g = b * 256 + tid;
        int m = g >> 11, off = (g & 2047) << 3;
        if (m == 0) {
            const floatx4 a = *(const floatx4*)(wl + off);
            const floatx4 c = *(const floatx4*)(wl + off + 4);
            *(bf16x8*)(wlb + off) = cvt8(a, c);
        } else if (m == 1) {
            floatx4 a = *(const floatx4*)(w0 + off);
            floatx4 c = *(const floatx4*)(w0 + off + 4);
            const floatx4 d = *(const floatx4*)(w1 + off);
            const floatx4 e = *(const floatx4*)(w1 + off + 4);
#pragma unroll
            for (int j = 0; j < 4; j++) { a[j] += d[j]; c[j] += e[j]; }
            *(bf16x8*)(w01b + off) = cvt8(a, c);
        } else {
            const floatx4 a = *(const floatx4*)(ow + off);
            const floatx4 c = *(const floatx4*)(ow + off + 4);
            *(bf16x8*)(owb + off) = cvt8(a, c);
        }
        if (g < 128) bias1[g] = bl[g] + b0[g] + b1[g];
        else if (g < 256) bias2[g - 128] = ob[g - 128];
    } else if (b < PREP_B + ZCUR_B) {
        if (tier >= 1) {
            int i = (b - PREP_B) * 256 + tid;
            if (i < NN) cur[i] = 0;
            if (b == PREP_B && tid == 0) *ovf_cnt = 0;
        }
    } else {
        // only present in tier-0 grid: zero aggr for the atomic-scatter fallback
        int i = (b - PREP_B - ZCUR_B) * 256 + tid;
        floatx4 z = {0.f, 0.f, 0.f, 0.f};
        ((floatx4*)aggr)[i] = z;
    }
}

// ===== K2: bucket append (1954) | x->bf16 (3125) — independent, co-scheduled =====
__global__ __launch_bounds__(256) void k_setup2(
    const int* __restrict__ edge, const float* __restrict__ x,
    int* __restrict__ cur, int* __restrict__ bucket,
    int* __restrict__ ovf_cnt, int* __restrict__ ovf,
    bf16* __restrict__ xb)
{
    const int b = blockIdx.x, tid = threadIdx.x;
    if (b < FILLB_B) {
        int e = b * 256 + tid;
        if (e >= NE) return;
        int dst = edge[e];
        int src = edge[NE + e];
        int pos = atomicAdd(&cur[dst], 1);
        if (pos < CAP) {
            bucket[dst * CAP + pos] = src;
        } else {   // statistically never — correctness valve via overflow list
            int oi = atomicAdd(ovf_cnt, 1);
            ovf[2 * oi] = dst;
            ovf[2 * oi + 1] = src;
        }
    } else {
        int off = ((b - FILLB_B) * 256 + tid) << 3;
        const floatx4 a = *(const floatx4*)(x + off);
        const floatx4 c = *(const floatx4*)(x + off + 4);
        *(bf16x8*)(xb + off) = cvt8(a, c);
    }
}

// ======== fallback atomic scatter (tier-0, proven; aggr pre-zeroed by K1) ========
__global__ __launch_bounds__(256) void k_scatter(const float* __restrict__ x,
                                                 const int* __restrict__ edge,
                                                 float* __restrict__ aggr) {
    int tid = blockIdx.x * 256 + threadIdx.x;
    int e = tid >> 5;
    int c = (tid & 31) << 2;
    int dst = edge[e];
    int src = edge[NE + e];
    const floatx4 v = *(const floatx4*)(x + src * HD + c);
    float* ap = aggr + dst * HD + c;
    unsafeAtomicAdd(ap + 0, v[0]);
    unsafeAtomicAdd(ap + 1, v[1]);
    unsafeAtomicAdd(ap + 2, v[2]);
    unsafeAtomicAdd(ap + 3, v[3]);
}

// ======== fused gather-aggregate + GEMM1 + GEMM2 with LDS overlay (~70.7 KB -> 2 blocks/CU) ====
// R4 structure + widened gather: ONE 8-edge group per iteration (32 uint4 loads issued
// straight-line = one latency exposure per 8 edges), simple while loop, no goto, DEFAULT
// launch bounds. R6's 2-deep goto pipeline + (256,2) spilled (VGPR pinned 128, 250MB scratch);
// this keeps the same bytes-in-flight with the R4-proven CFG shape. Spill detector: WRITE_SIZE.
__global__ __launch_bounds__(256) void k_fused(
    const float* __restrict__ aggr, const float* __restrict__ x, const bf16* __restrict__ xb,
    int tier,
    const int* __restrict__ cur, const int* __restrict__ bucket,
    const int* __restrict__ ovf_cnt, const int* __restrict__ ovf,
    const bf16* __restrict__ wlb, const bf16* __restrict__ w01b, const bf16* __restrict__ owb,
    const float* __restrict__ bias1, const float* __restrict__ bias2,
    float* __restrict__ out)
{
    __shared__ bf16 sA[128 * 136];        // wl, then ow
    __shared__ bf16 sB[128 * 136];        // w01, then tp (h transpose)
    __shared__ float b1_s[128], b2_s[128];
    float* tp = (float*)sB;               // [4][16][132]
    const int tid = threadIdx.x;

#pragma unroll
    for (int it = 0; it < 8; it++) {
        int i = tid + it * 256;
        int r = i >> 4;
        int o = (i & 15) << 3;
        *(bf16x8*)(sA + r * 136 + o) = *(const bf16x8*)(wlb  + r * 128 + o);
        *(bf16x8*)(sB + r * 136 + o) = *(const bf16x8*)(w01b + r * 128 + o);
    }
    if (tid < 128) { b1_s[tid] = bias1[tid]; b2_s[tid] = bias2[tid]; }
    // staging sync deferred to after the register gather (gather touches no LDS),
    // so staging stores drain while the gather runs.

    const int lane = tid & 63;
    const int wv   = tid >> 6;
    const int ln   = lane & 15;
    const int quad = lane >> 4;
    const int row0 = blockIdx.x * 64 + wv * 16;
    const int arow = row0 + ln;
    const bool aok = arow < NN;
    const int q8   = quad * 8;

    floatx4 ag0[4] = {};   // ag0[kc] = aggregated feats kc*32+q8 .. +3
    floatx4 ag1[4] = {};   // ag1[kc] = aggregated feats kc*32+q8+4 .. +7

    // preload this row's x-features (GEMM1 a_x operand) so the loads ride under the gather
    bf16x8 ax[4] = {zero8(), zero8(), zero8(), zero8()};
    if (tier && aok) {
#pragma unroll
        for (int kc = 0; kc < 4; kc++)
            ax[kc] = *(const bf16x8*)(xb + (size_t)arow * HD + kc * 32 + q8);
    }

    if (tier) {
        int deg = 0, n = 0;
        if (aok) { deg = cur[arow]; n = (deg < CAP) ? deg : CAP; }
        const int* bk = bucket + (size_t)arow * CAP;
        int t = 0;
        uint4 a00, a01, a02, a03, a10, a11, a12, a13,
              a20, a21, a22, a23, a30, a31, a32, a33;
        uint4 b00, b01, b02, b03, b10, b11, b12, b13,
              b20, b21, b22, b23, b30, b31, b32, b33;
        if (t + 3 < n) {
            // reading index slots past deg (but within the row) is safe: row is fully
            // allocated; garbage values are never used for loads (all GLOADs guarded).
            int4 si = *(const int4*)(bk);
            int4 sj = *(const int4*)(bk + 4);
            while (t + 7 < n) {
                const int4 si_n = *(const int4*)(bk + t + 8);    // prefetch next 8 indices
                const int4 sj_n = *(const int4*)(bk + t + 12);   // (may read past row end of
                GLOAD16(a, si);                                  //  last node: still in ws)
                GLOAD16(b, sj);                                  // 32 uint4 in flight
                GUNPACK(a);
                GUNPACK(b);
                si = si_n; sj = sj_n;
                t += 8;
            }
            if (t + 3 < n) {               // 4-edge tail; indices already prefetched in si
                GLOAD16(a, si);
                GUNPACK(a);
                t += 4;
            }
        }
        for (; t < n; t++) {
            const bf16* r0 = xb + (size_t)bk[t] * HD + q8;
            const uint4 e0 = *(const uint4*)(r0);
            const uint4 e1 = *(const uint4*)(r0 + 32);
            const uint4 e2 = *(const uint4*)(r0 + 64);
            const uint4 e3 = *(const uint4*)(r0 + 96);
            addrow(ag0[0], ag1[0], e0); addrow(ag0[1], ag1[1], e1);
            addrow(ag0[2], ag1[2], e2); addrow(ag0[3], ag1[3], e3);
        }
        if (deg > CAP) {                  // never fires for the bench inputs
            const int m = *ovf_cnt;
            for (int i = 0; i < m; i++) {
                if (ovf[2 * i] == arow) {
                    const bf16* r0 = xb + (size_t)ovf[2 * i + 1] * HD + q8;
                    const uint4 e0 = *(const uint4*)(r0);
                    const uint4 e1 = *(const uint4*)(r0 + 32);
                    const uint4 e2 = *(const uint4*)(r0 + 64);
                    const uint4 e3 = *(const uint4*)(r0 + 96);
                    addrow(ag0[0], ag1[0], e0); addrow(ag0[1], ag1[1], e1);
                    addrow(ag0[2], ag1[2], e2); addrow(ag0[3], ag1[3], e3);
                }
            }
        }
    } else if (aok) {                     // tier-0: aggr came from the atomic scatter
#pragma unroll
        for (int kc = 0; kc < 4; kc++) {
            ag0[kc] = *(const floatx4*)(aggr + (size_t)arow * HD + kc * 32 + q8);
            ag1[kc] = *(const floatx4*)(aggr + (size_t)arow * HD + kc * 32 + q8 + 4);
        }
    }

    __syncthreads();                      // weights staged; gather results live in regs

    floatx4 acc[8] = {};

    // ---- GEMM1 ----
#pragma unroll
    for (int kc = 0; kc < 4; kc++) {
        const int k0 = kc * 32 + q8;
        bf16x8 a_hi, a_lo;
        split8(ag0[kc], ag1[kc], a_hi, a_lo);
        bf16x8 a_x = ax[kc];
        if (!tier && aok) {
            const floatx4 g0 = *(const floatx4*)(x + (size_t)arow * HD + k0);
            const floatx4 g1 = *(const floatx4*)(x + (size_t)arow * HD + k0 + 4);
            a_x = cvt8(g0, g1);
        }
#pragma unroll
        for (int nc = 0; nc < 8; nc++) {
            const bf16x8 bw  = *(const bf16x8*)(sA + (nc * 16 + ln) * 136 + k0);
            const bf16x8 bw2 = *(const bf16x8*)(sB + (nc * 16 + ln) * 136 + k0);
            acc[nc] = __builtin_amdgcn_mfma_f32_16x16x32_bf16(a_hi, bw,  acc[nc], 0, 0, 0);
            acc[nc] = __builtin_amdgcn_mfma_f32_16x16x32_bf16(a_lo, bw,  acc[nc], 0, 0, 0);
            acc[nc] = __builtin_amdgcn_mfma_f32_16x16x32_bf16(a_x,  bw2, acc[nc], 0, 0, 0);
        }
    }
    __syncthreads();

    // ---- overlay: restage ow into sA; park relu(h) into tp (over sB) ----
#pragma unroll
    for (int it = 0; it < 8; it++) {
        int i = tid + it * 256;
        int r = i >> 4;
        int o = (i & 15) << 3;
        *(bf16x8*)(sA + r * 136 + o) = *(const bf16x8*)(owb + r * 128 + o);
    }
#pragma unroll
    for (int nc = 0; nc < 8; nc++) {
        const int col = nc * 16 + ln;
        const float bv = b1_s[col];
#pragma unroll
        for (int r = 0; r < 4; r++) {
            float v = acc[nc][r] + bv;
            tp[wv * 2112 + (quad * 4 + r) * 132 + col] = (v > 0.f ? v : 0.f);
        }
        acc[nc][0] = acc[nc][1] = acc[nc][2] = acc[nc][3] = 0.f;
    }
    __syncthreads();

    // ---- GEMM2 ----
#pragma unroll
    for (int kc = 0; kc < 4; kc++) {
        const int k0 = kc * 32 + q8;
        const floatx4 f0 = *(const floatx4*)(tp + wv * 2112 + ln * 132 + k0);
        const floatx4 f1 = *(const floatx4*)(tp + wv * 2112 + ln * 132 + k0 + 4);
        bf16x8 a_hi, a_lo;
        split8(f0, f1, a_hi, a_lo);
#pragma unroll
        for (int nc = 0; nc < 8; nc++) {
            const bf16x8 bw = *(const bf16x8*)(sA + (nc * 16 + ln) * 136 + k0);
            acc[nc] = __builtin_amdgcn_mfma_f32_16x16x32_bf16(a_hi, bw, acc[nc], 0, 0, 0);
            acc[nc] = __builtin_amdgcn_mfma_f32_16x16x32_bf16(a_lo, bw, acc[nc], 0, 0, 0);
        }
    }

#pragma unroll
    for (int nc = 0; nc < 8; nc++) {
        const int col = nc * 16 + ln;
        const float bv = b2_s[col];
#pragma unroll
        for (int r = 0; r < 4; r++) {
            const int row = row0 + quad * 4 + r;
            if (row < NN) out[row * 128 + col] = acc[nc][r] + bv;
        }
    }
}

extern "C" void kernel_launch(void* const* d_in, const int* in_sizes, int n_in,
                              void* d_out, int out_size, void* d_ws, size_t ws_size,
                              hipStream_t stream) {
    const float* x_a     = (const float*)d_in[0];
    const int*   edge_ba = (const int*)d_in[3];
    const float* c1_w0_w = (const float*)d_in[10];
    const float* c1_w0_b = (const float*)d_in[11];
    const float* c1_wl_w = (const float*)d_in[12];
    const float* c1_wl_b = (const float*)d_in[13];
    const float* c1_w1_w = (const float*)d_in[14];
    const float* c1_w1_b = (const float*)d_in[15];
    const float* out_w   = (const float*)d_in[16];
    const float* out_b   = (const float*)d_in[17];

    char* p = (char*)d_ws;
    float* aggr  = (float*)p;   p += (size_t)NN * HD * 4;     // 25.6 MB (tier-0 fallback only)
    bf16*  wlb   = (bf16*)p;    p += 32768;
    bf16*  w01b  = (bf16*)p;    p += 32768;
    bf16*  owb   = (bf16*)p;    p += 32768;
    float* bias1 = (float*)p;   p += 512;
    float* bias2 = (float*)p;   p += 512;
    const size_t WS_FALL = (size_t)(p - (char*)d_ws);         // ~25.7 MB
    int*   cur    = (int*)p;    p += 200704;                  // NN ints (padded)
    int*   bucket = (int*)p;    p += (size_t)NN * CAP * 4;    // 25.6 MB
    bf16*  xb     = (bf16*)p;   p += (size_t)NN * HD * 2;     // 12.8 MB
    int*   ovf_cnt= (int*)p;    p += 256;
    int*   ovf    = (int*)p;    p += (size_t)NE * 2 * 4;      // 4 MB overflow (dst,src) pairs
    const size_t WS_BUCKET = (size_t)(p - (char*)d_ws);       // ~68.5 MB (ws = 256 MiB)
    (void)WS_FALL;

    const int tier = (ws_size >= WS_BUCKET) ? 1 : 0;

    const int k1_grid = tier ? (PREP_B + ZCUR_B) : (PREP_B + ZCUR_B + ZAGGR_B);
    k_setup1<<<k1_grid, 256, 0, stream>>>(c1_wl_w, c1_w0_w, c1_w1_w,
                                          c1_wl_b, c1_w0_b, c1_w1_b,
                                          out_w, out_b,
                                          wlb, w01b, owb, bias1, bias2,
                                          aggr, cur, ovf_cnt, tier);

    if (tier) {
        k_setup2<<<K2_B, 256, 0, stream>>>(edge_ba, x_a, cur, bucket, ovf_cnt, ovf, xb);
    } else {
        k_scatter<<<NE * 32 / 256, 256, 0, stream>>>(x_a, edge_ba, aggr);
    }

    k_fused<<<(NN + 63) / 64, 256, 0, stream>>>(aggr, x_a, xb, tier,
                                                cur, bucket, ovf_cnt, ovf,
                                                wlb, w01b, owb, bias1, bias2,
                                                (float*)d_out);
}

// Round 8
// 194.075 us; speedup vs baseline: 1.3413x; 1.0767x over previous
//
#include <hip/hip_runtime.h>
#include <hip/hip_bf16.h>

#define NN 50000
#define NE 500000
#define HD 128
#define CAP 128
#define PREP_B 24
#define ZCUR_B ((NN + 255) / 256)          // 196
#define ZAGGR_B 6250
#define FILLB_B ((NE + 255) / 256)         // 1954
#define XCONV_B 3125
#define K2_B (FILLB_B + XCONV_B)           // 5079

typedef __bf16 bf16;
typedef __attribute__((ext_vector_type(8))) __bf16 bf16x8;
typedef __attribute__((ext_vector_type(4))) float floatx4;

__device__ inline float u2f(unsigned int lo16) {
    union { unsigned int i; float f; } c; c.i = lo16 << 16; return c.f;
}

__device__ inline bf16x8 cvt8(floatx4 a, floatx4 b) {
    bf16x8 r;
#pragma unroll
    for (int j = 0; j < 4; j++) { r[j] = (bf16)a[j]; r[j + 4] = (bf16)b[j]; }
    return r;
}

__device__ inline void split8(const floatx4 f0, const floatx4 f1, bf16x8& hi, bf16x8& lo) {
#pragma unroll
    for (int j = 0; j < 4; j++) {
        float a = f0[j]; bf16 h = (bf16)a; hi[j] = h; lo[j] = (bf16)(a - (float)h);
        float b = f1[j]; bf16 g = (bf16)b; hi[j + 4] = g; lo[j + 4] = (bf16)(b - (float)g);
    }
}

__device__ inline bf16x8 zero8() {
    bf16x8 v;
#pragma unroll
    for (int j = 0; j < 8; j++) v[j] = (bf16)0.f;
    return v;
}

// accumulate 8 bf16 (one uint4) into two floatx4 (feats 0..3 -> f0, 4..7 -> f1)
__device__ inline void addrow(floatx4& f0, floatx4& f1, const uint4 v) {
    f0[0] += u2f(v.x & 0xffff); f0[1] += u2f(v.x >> 16);
    f0[2] += u2f(v.y & 0xffff); f0[3] += u2f(v.y >> 16);
    f1[0] += u2f(v.z & 0xffff); f1[1] += u2f(v.z >> 16);
    f1[2] += u2f(v.w & 0xffff); f1[3] += u2f(v.w >> 16);
}

// ===== K1: weights->bf16 (24) | zero cur + ovf_cnt + xb zero-row (196) | [tier0: zero aggr] ====
__global__ __launch_bounds__(256) void k_setup1(
    const float* __restrict__ wl, const float* __restrict__ w0, const float* __restrict__ w1,
    const float* __restrict__ bl, const float* __restrict__ b0, const float* __restrict__ b1,
    const float* __restrict__ ow, const float* __restrict__ ob,
    bf16* __restrict__ wlb, bf16* __restrict__ w01b, bf16* __restrict__ owb,
    float* __restrict__ bias1, float* __restrict__ bias2,
    float* __restrict__ aggr, int* __restrict__ cur, int* __restrict__ ovf_cnt,
    bf16* __restrict__ xb, int tier)
{
    const int b = blockIdx.x, tid = threadIdx.x;
    if (b < PREP_B) {
        int g = b * 256 + tid;
        int m = g >> 11, off = (g & 2047) << 3;
        if (m == 0) {
            const floatx4 a = *(const floatx4*)(wl + off);
            const floatx4 c = *(const floatx4*)(wl + off + 4);
            *(bf16x8*)(wlb + off) = cvt8(a, c);
        } else if (m == 1) {
            floatx4 a = *(const floatx4*)(w0 + off);
            floatx4 c = *(const floatx4*)(w0 + off + 4);
            const floatx4 d = *(const floatx4*)(w1 + off);
            const floatx4 e = *(const floatx4*)(w1 + off + 4);
#pragma unroll
            for (int j = 0; j < 4; j++) { a[j] += d[j]; c[j] += e[j]; }
            *(bf16x8*)(w01b + off) = cvt8(a, c);
        } else {
            const floatx4 a = *(const floatx4*)(ow + off);
            const floatx4 c = *(const floatx4*)(ow + off + 4);
            *(bf16x8*)(owb + off) = cvt8(a, c);
        }
        if (g < 128) bias1[g] = bl[g] + b0[g] + b1[g];
        else if (g < 256) bias2[g - 128] = ob[g - 128];
    } else if (b < PREP_B + ZCUR_B) {
        if (tier >= 1) {
            int i = (b - PREP_B) * 256 + tid;
            if (i < NN) cur[i] = 0;
            else if (i < NN + 16) *(bf16x8*)(xb + (size_t)NN * HD + (i - NN) * 8) = zero8();
            if (b == PREP_B && tid == 0) *ovf_cnt = 0;
        }
    } else {
        // only present in tier-0 grid: zero aggr for the atomic-scatter fallback
        int i = (b - PREP_B - ZCUR_B) * 256 + tid;
        floatx4 z = {0.f, 0.f, 0.f, 0.f};
        ((floatx4*)aggr)[i] = z;
    }
}

// ===== K2: bucket append (1954) | x->bf16 (3125) — independent, co-scheduled =====
__global__ __launch_bounds__(256) void k_setup2(
    const int* __restrict__ edge, const float* __restrict__ x,
    int* __restrict__ cur, int* __restrict__ bucket,
    int* __restrict__ ovf_cnt, int* __restrict__ ovf,
    bf16* __restrict__ xb)
{
    const int b = blockIdx.x, tid = threadIdx.x;
    if (b < FILLB_B) {
        int e = b * 256 + tid;
        if (e >= NE) return;
        int dst = edge[e];
        int src = edge[NE + e];
        int pos = atomicAdd(&cur[dst], 1);
        if (pos < CAP) {
            bucket[dst * CAP + pos] = src;
        } else {   // statistically never — correctness valve via overflow list
            int oi = atomicAdd(ovf_cnt, 1);
            ovf[2 * oi] = dst;
            ovf[2 * oi + 1] = src;
        }
    } else {
        int off = ((b - FILLB_B) * 256 + tid) << 3;
        const floatx4 a = *(const floatx4*)(x + off);
        const floatx4 c = *(const floatx4*)(x + off + 4);
        *(bf16x8*)(xb + off) = cvt8(a, c);
    }
}

// ======== fallback atomic scatter (tier-0, proven; aggr pre-zeroed by K1) ========
__global__ __launch_bounds__(256) void k_scatter(const float* __restrict__ x,
                                                 const int* __restrict__ edge,
                                                 float* __restrict__ aggr) {
    int tid = blockIdx.x * 256 + threadIdx.x;
    int e = tid >> 5;
    int c = (tid & 31) << 2;
    int dst = edge[e];
    int src = edge[NE + e];
    const floatx4 v = *(const floatx4*)(x + src * HD + c);
    float* ap = aggr + dst * HD + c;
    unsafeAtomicAdd(ap + 0, v[0]);
    unsafeAtomicAdd(ap + 1, v[1]);
    unsafeAtomicAdd(ap + 2, v[2]);
    unsafeAtomicAdd(ap + 3, v[3]);
}

// ======== fused gather-aggregate + GEMM1 + GEMM2 with LDS overlay (~70.7 KB -> 2 blocks/CU) ====
// R4-proven gather shape (4-edge groups, rolling int4 index prefetch, 16 loads in flight),
// with the divergent scalar tail ELIMINATED: out-of-range slots clamp to dummy node NN whose
// xb row is all zeros (gathering zeros is a no-op). One uniform pipelined loop, no drain,
// no singles. Wave-max exposures ~7 -> ~5. Spill detector: WRITE_SIZE (must stay 25 MB).
__global__ __launch_bounds__(256) void k_fused(
    const float* __restrict__ aggr, const float* __restrict__ x, const bf16* __restrict__ xb,
    int tier,
    const int* __restrict__ cur, const int* __restrict__ bucket,
    const int* __restrict__ ovf_cnt, const int* __restrict__ ovf,
    const bf16* __restrict__ wlb, const bf16* __restrict__ w01b, const bf16* __restrict__ owb,
    const float* __restrict__ bias1, const float* __restrict__ bias2,
    float* __restrict__ out)
{
    __shared__ bf16 sA[128 * 136];        // wl, then ow
    __shared__ bf16 sB[128 * 136];        // w01, then tp (h transpose)
    __shared__ float b1_s[128], b2_s[128];
    float* tp = (float*)sB;               // [4][16][132]
    const int tid = threadIdx.x;

#pragma unroll
    for (int it = 0; it < 8; it++) {
        int i = tid + it * 256;
        int r = i >> 4;
        int o = (i & 15) << 3;
        *(bf16x8*)(sA + r * 136 + o) = *(const bf16x8*)(wlb  + r * 128 + o);
        *(bf16x8*)(sB + r * 136 + o) = *(const bf16x8*)(w01b + r * 128 + o);
    }
    if (tid < 128) { b1_s[tid] = bias1[tid]; b2_s[tid] = bias2[tid]; }
    // staging sync deferred to after the register gather (gather touches no LDS),
    // so staging stores drain while the gather runs.

    const int lane = tid & 63;
    const int wv   = tid >> 6;
    const int ln   = lane & 15;
    const int quad = lane >> 4;
    const int row0 = blockIdx.x * 64 + wv * 16;
    const int arow = row0 + ln;
    const bool aok = arow < NN;
    const int q8   = quad * 8;

    floatx4 ag0[4] = {};   // ag0[kc] = aggregated feats kc*32+q8 .. +3
    floatx4 ag1[4] = {};   // ag1[kc] = aggregated feats kc*32+q8+4 .. +7

    // preload this row's x-features (GEMM1 a_x operand) so the loads ride under the gather
    bf16x8 ax[4] = {zero8(), zero8(), zero8(), zero8()};
    if (tier && aok) {
#pragma unroll
        for (int kc = 0; kc < 4; kc++)
            ax[kc] = *(const bf16x8*)(xb + (size_t)arow * HD + kc * 32 + q8);
    }

    if (tier) {
        int deg = 0, n = 0;
        if (aok) { deg = cur[arow]; n = (deg < CAP) ? deg : CAP; }
        const int* bk = bucket + (size_t)arow * CAP;
        if (n > 0) {
            int4 s = *(const int4*)(bk);               // bucket rows 512B-aligned
            int t = 0;
            while (t < n) {
                const int4 sn = *(const int4*)(bk + t + 4);   // rolling prefetch (reads past
                                                              // row end are in-ws, unused)
                const int i0 = s.x;                           // t < n always
                const int i1 = (t + 1 < n) ? s.y : NN;        // NN = zero row -> no-op add
                const int i2 = (t + 2 < n) ? s.z : NN;
                const int i3 = (t + 3 < n) ? s.w : NN;
                const uint4* p0 = (const uint4*)(xb + (size_t)i0 * HD + q8);
                const uint4* p1 = (const uint4*)(xb + (size_t)i1 * HD + q8);
                const uint4* p2 = (const uint4*)(xb + (size_t)i2 * HD + q8);
                const uint4* p3 = (const uint4*)(xb + (size_t)i3 * HD + q8);
                // issue all 16 loads straight-line, then unpack (max MLP)
                const uint4 v00 = p0[0], v01 = p0[4], v02 = p0[8], v03 = p0[12];
                const uint4 v10 = p1[0], v11 = p1[4], v12 = p1[8], v13 = p1[12];
                const uint4 v20 = p2[0], v21 = p2[4], v22 = p2[8], v23 = p2[12];
                const uint4 v30 = p3[0], v31 = p3[4], v32 = p3[8], v33 = p3[12];
                addrow(ag0[0], ag1[0], v00); addrow(ag0[1], ag1[1], v01);
                addrow(ag0[2], ag1[2], v02); addrow(ag0[3], ag1[3], v03);
                addrow(ag0[0], ag1[0], v10); addrow(ag0[1], ag1[1], v11);
                addrow(ag0[2], ag1[2], v12); addrow(ag0[3], ag1[3], v13);
                addrow(ag0[0], ag1[0], v20); addrow(ag0[1], ag1[1], v21);
                addrow(ag0[2], ag1[2], v22); addrow(ag0[3], ag1[3], v23);
                addrow(ag0[0], ag1[0], v30); addrow(ag0[1], ag1[1], v31);
                addrow(ag0[2], ag1[2], v32); addrow(ag0[3], ag1[3], v33);
                s = sn;
                t += 4;
            }
        }
        if (deg > CAP) {                  // never fires for the bench inputs
            const int m = *ovf_cnt;
            for (int i = 0; i < m; i++) {
                if (ovf[2 * i] == arow) {
                    const bf16* r0 = xb + (size_t)ovf[2 * i + 1] * HD + q8;
                    const uint4 e0 = *(const uint4*)(r0);
                    const uint4 e1 = *(const uint4*)(r0 + 32);
                    const uint4 e2 = *(const uint4*)(r0 + 64);
                    const uint4 e3 = *(const uint4*)(r0 + 96);
                    addrow(ag0[0], ag1[0], e0); addrow(ag0[1], ag1[1], e1);
                    addrow(ag0[2], ag1[2], e2); addrow(ag0[3], ag1[3], e3);
                }
            }
        }
    } else if (aok) {                     // tier-0: aggr came from the atomic scatter
#pragma unroll
        for (int kc = 0; kc < 4; kc++) {
            ag0[kc] = *(const floatx4*)(aggr + (size_t)arow * HD + kc * 32 + q8);
            ag1[kc] = *(const floatx4*)(aggr + (size_t)arow * HD + kc * 32 + q8 + 4);
        }
    }

    __syncthreads();                      // weights staged; gather results live in regs

    floatx4 acc[8] = {};

    // ---- GEMM1 ----
#pragma unroll
    for (int kc = 0; kc < 4; kc++) {
        const int k0 = kc * 32 + q8;
        bf16x8 a_hi, a_lo;
        split8(ag0[kc], ag1[kc], a_hi, a_lo);
        bf16x8 a_x = ax[kc];
        if (!tier && aok) {
            const floatx4 g0 = *(const floatx4*)(x + (size_t)arow * HD + k0);
            const floatx4 g1 = *(const floatx4*)(x + (size_t)arow * HD + k0 + 4);
            a_x = cvt8(g0, g1);
        }
#pragma unroll
        for (int nc = 0; nc < 8; nc++) {
            const bf16x8 bw  = *(const bf16x8*)(sA + (nc * 16 + ln) * 136 + k0);
            const bf16x8 bw2 = *(const bf16x8*)(sB + (nc * 16 + ln) * 136 + k0);
            acc[nc] = __builtin_amdgcn_mfma_f32_16x16x32_bf16(a_hi, bw,  acc[nc], 0, 0, 0);
            acc[nc] = __builtin_amdgcn_mfma_f32_16x16x32_bf16(a_lo, bw,  acc[nc], 0, 0, 0);
            acc[nc] = __builtin_amdgcn_mfma_f32_16x16x32_bf16(a_x,  bw2, acc[nc], 0, 0, 0);
        }
    }
    __syncthreads();

    // ---- overlay: restage ow into sA; park relu(h) into tp (over sB) ----
#pragma unroll
    for (int it = 0; it < 8; it++) {
        int i = tid + it * 256;
        int r = i >> 4;
        int o = (i & 15) << 3;
        *(bf16x8*)(sA + r * 136 + o) = *(const bf16x8*)(owb + r * 128 + o);
    }
#pragma unroll
    for (int nc = 0; nc < 8; nc++) {
        const int col = nc * 16 + ln;
        const float bv = b1_s[col];
#pragma unroll
        for (int r = 0; r < 4; r++) {
            float v = acc[nc][r] + bv;
            tp[wv * 2112 + (quad * 4 + r) * 132 + col] = (v > 0.f ? v : 0.f);
        }
        acc[nc][0] = acc[nc][1] = acc[nc][2] = acc[nc][3] = 0.f;
    }
    __syncthreads();

    // ---- GEMM2 ----
#pragma unroll
    for (int kc = 0; kc < 4; kc++) {
        const int k0 = kc * 32 + q8;
        const floatx4 f0 = *(const floatx4*)(tp + wv * 2112 + ln * 132 + k0);
        const floatx4 f1 = *(const floatx4*)(tp + wv * 2112 + ln * 132 + k0 + 4);
        bf16x8 a_hi, a_lo;
        split8(f0, f1, a_hi, a_lo);
#pragma unroll
        for (int nc = 0; nc < 8; nc++) {
            const bf16x8 bw = *(const bf16x8*)(sA + (nc * 16 + ln) * 136 + k0);
            acc[nc] = __builtin_amdgcn_mfma_f32_16x16x32_bf16(a_hi, bw, acc[nc], 0, 0, 0);
            acc[nc] = __builtin_amdgcn_mfma_f32_16x16x32_bf16(a_lo, bw, acc[nc], 0, 0, 0);
        }
    }

#pragma unroll
    for (int nc = 0; nc < 8; nc++) {
        const int col = nc * 16 + ln;
        const float bv = b2_s[col];
#pragma unroll
        for (int r = 0; r < 4; r++) {
            const int row = row0 + quad * 4 + r;
            if (row < NN) out[row * 128 + col] = acc[nc][r] + bv;
        }
    }
}

extern "C" void kernel_launch(void* const* d_in, const int* in_sizes, int n_in,
                              void* d_out, int out_size, void* d_ws, size_t ws_size,
                              hipStream_t stream) {
    const float* x_a     = (const float*)d_in[0];
    const int*   edge_ba = (const int*)d_in[3];
    const float* c1_w0_w = (const float*)d_in[10];
    const float* c1_w0_b = (const float*)d_in[11];
    const float* c1_wl_w = (const float*)d_in[12];
    const float* c1_wl_b = (const float*)d_in[13];
    const float* c1_w1_w = (const float*)d_in[14];
    const float* c1_w1_b = (const float*)d_in[15];
    const float* out_w   = (const float*)d_in[16];
    const float* out_b   = (const float*)d_in[17];

    char* p = (char*)d_ws;
    float* aggr  = (float*)p;   p += (size_t)NN * HD * 4;     // 25.6 MB (tier-0 fallback only)
    bf16*  wlb   = (bf16*)p;    p += 32768;
    bf16*  w01b  = (bf16*)p;    p += 32768;
    bf16*  owb   = (bf16*)p;    p += 32768;
    float* bias1 = (float*)p;   p += 512;
    float* bias2 = (float*)p;   p += 512;
    const size_t WS_FALL = (size_t)(p - (char*)d_ws);         // ~25.7 MB
    int*   cur    = (int*)p;    p += 200704;                  // NN ints (padded)
    int*   bucket = (int*)p;    p += (size_t)NN * CAP * 4;    // 25.6 MB
    bf16*  xb     = (bf16*)p;   p += (size_t)(NN + 2) * HD * 2; // 12.8 MB + zero row NN
    int*   ovf_cnt= (int*)p;    p += 256;
    int*   ovf    = (int*)p;    p += (size_t)NE * 2 * 4;      // 4 MB overflow (dst,src) pairs
    const size_t WS_BUCKET = (size_t)(p - (char*)d_ws);       // ~68.5 MB (ws = 256 MiB)
    (void)WS_FALL;

    const int tier = (ws_size >= WS_BUCKET) ? 1 : 0;

    const int k1_grid = tier ? (PREP_B + ZCUR_B) : (PREP_B + ZCUR_B + ZAGGR_B);
    k_setup1<<<k1_grid, 256, 0, stream>>>(c1_wl_w, c1_w0_w, c1_w1_w,
                                          c1_wl_b, c1_w0_b, c1_w1_b,
                                          out_w, out_b,
                                          wlb, w01b, owb, bias1, bias2,
                                          aggr, cur, ovf_cnt, xb, tier);

    if (tier) {
        k_setup2<<<K2_B, 256, 0, stream>>>(edge_ba, x_a, cur, bucket, ovf_cnt, ovf, xb);
    } else {
        k_scatter<<<NE * 32 / 256, 256, 0, stream>>>(x_a, edge_ba, aggr);
    }

    k_fused<<<(NN + 63) / 64, 256, 0, stream>>>(aggr, x_a, xb, tier,
                                                cur, bucket, ovf_cnt, ovf,
                                                wlb, w01b, owb, bias1, bias2,
                                                (float*)d_out);
}

// Round 10
// 192.649 us; speedup vs baseline: 1.3512x; 1.0074x over previous
//
#include <hip/hip_runtime.h>
#include <hip/hip_bf16.h>

#define NN 50000
#define NE 500000
#define HD 128
#define CAP 128
#define PREP_B 24
#define ZCUR_B ((NN + 255) / 256)          // 196
#define ZAGGR_B 6250
#define FILLB_B ((NE + 255) / 256)         // 1954
#define XCONV_B 3125
#define K2_B (FILLB_B + XCONV_B)           // 5079

typedef __bf16 bf16;
typedef __attribute__((ext_vector_type(8))) __bf16 bf16x8;
typedef __attribute__((ext_vector_type(4))) float floatx4;

__device__ inline float u2f(unsigned int lo16) {
    union { unsigned int i; float f; } c; c.i = lo16 << 16; return c.f;
}

__device__ inline bf16x8 cvt8(floatx4 a, floatx4 b) {
    bf16x8 r;
#pragma unroll
    for (int j = 0; j < 4; j++) { r[j] = (bf16)a[j]; r[j + 4] = (bf16)b[j]; }
    return r;
}

__device__ inline void split8(const floatx4 f0, const floatx4 f1, bf16x8& hi, bf16x8& lo) {
#pragma unroll
    for (int j = 0; j < 4; j++) {
        float a = f0[j]; bf16 h = (bf16)a; hi[j] = h; lo[j] = (bf16)(a - (float)h);
        float b = f1[j]; bf16 g = (bf16)b; hi[j + 4] = g; lo[j + 4] = (bf16)(b - (float)g);
    }
}

__device__ inline bf16x8 zero8() {
    bf16x8 v;
#pragma unroll
    for (int j = 0; j < 8; j++) v[j] = (bf16)0.f;
    return v;
}

// accumulate 8 bf16 (one uint4) into two floatx4
__device__ inline void addrow(floatx4& f0, floatx4& f1, const uint4 v) {
    f0[0] += u2f(v.x & 0xffff); f0[1] += u2f(v.x >> 16);
    f0[2] += u2f(v.y & 0xffff); f0[3] += u2f(v.y >> 16);
    f1[0] += u2f(v.z & 0xffff); f1[1] += u2f(v.z >> 16);
    f1[2] += u2f(v.w & 0xffff); f1[3] += u2f(v.w >> 16);
}

// ===== K1: weights->bf16 (24) | zero cur + ovf_cnt + xb zero-row (196) | [tier0: zero aggr] ====
__global__ __launch_bounds__(256) void k_setup1(
    const float* __restrict__ wl, const float* __restrict__ w0, const float* __restrict__ w1,
    const float* __restrict__ bl, const float* __restrict__ b0, const float* __restrict__ b1,
    const float* __restrict__ ow, const float* __restrict__ ob,
    bf16* __restrict__ wlb, bf16* __restrict__ w01b, bf16* __restrict__ owb,
    float* __restrict__ bias1, float* __restrict__ bias2,
    float* __restrict__ aggr, int* __restrict__ cur, int* __restrict__ ovf_cnt,
    bf16* __restrict__ xb, int tier)
{
    const int b = blockIdx.x, tid = threadIdx.x;
    if (b < PREP_B) {
        int g = b * 256 + tid;
        int m = g >> 11, off = (g & 2047) << 3;
        if (m == 0) {
            const floatx4 a = *(const floatx4*)(wl + off);
            const floatx4 c = *(const floatx4*)(wl + off + 4);
            *(bf16x8*)(wlb + off) = cvt8(a, c);
        } else if (m == 1) {
            floatx4 a = *(const floatx4*)(w0 + off);
            floatx4 c = *(const floatx4*)(w0 + off + 4);
            const floatx4 d = *(const floatx4*)(w1 + off);
            const floatx4 e = *(const floatx4*)(w1 + off + 4);
#pragma unroll
            for (int j = 0; j < 4; j++) { a[j] += d[j]; c[j] += e[j]; }
            *(bf16x8*)(w01b + off) = cvt8(a, c);
        } else {
            const floatx4 a = *(const floatx4*)(ow + off);
            const floatx4 c = *(const floatx4*)(ow + off + 4);
            *(bf16x8*)(owb + off) = cvt8(a, c);
        }
        if (g < 128) bias1[g] = bl[g] + b0[g] + b1[g];
        else if (g < 256) bias2[g - 128] = ob[g - 128];
    } else if (b < PREP_B + ZCUR_B) {
        if (tier >= 1) {
            int i = (b - PREP_B) * 256 + tid;
            if (i < NN) cur[i] = 0;
            else if (i < NN + 16) *(bf16x8*)(xb + (size_t)NN * HD + (i - NN) * 8) = zero8();
            if (b == PREP_B && tid == 0) *ovf_cnt = 0;
        }
    } else {
        // only present in tier-0 grid: zero aggr for the atomic-scatter fallback
        int i = (b - PREP_B - ZCUR_B) * 256 + tid;
        floatx4 z = {0.f, 0.f, 0.f, 0.f};
        ((floatx4*)aggr)[i] = z;
    }
}

// ===== K2: bucket append (1954) | x->bf16 (3125) — independent, co-scheduled =====
__global__ __launch_bounds__(256) void k_setup2(
    const int* __restrict__ edge, const float* __restrict__ x,
    int* __restrict__ cur, int* __restrict__ bucket,
    int* __restrict__ ovf_cnt, int* __restrict__ ovf,
    bf16* __restrict__ xb)
{
    const int b = blockIdx.x, tid = threadIdx.x;
    if (b < FILLB_B) {
        int e = b * 256 + tid;
        if (e >= NE) return;
        int dst = edge[e];
        int src = edge[NE + e];
        int pos = atomicAdd(&cur[dst], 1);
        if (pos < CAP) {
            bucket[dst * CAP + pos] = src;
        } else {   // statistically never — correctness valve via overflow list
            int oi = atomicAdd(ovf_cnt, 1);
            ovf[2 * oi] = dst;
            ovf[2 * oi + 1] = src;
        }
    } else {
        int off = ((b - FILLB_B) * 256 + tid) << 3;
        const floatx4 a = *(const floatx4*)(x + off);
        const floatx4 c = *(const floatx4*)(x + off + 4);
        *(bf16x8*)(xb + off) = cvt8(a, c);
    }
}

// ======== fallback atomic scatter (tier-0, proven; aggr pre-zeroed by K1) ========
__global__ __launch_bounds__(256) void k_scatter(const float* __restrict__ x,
                                                 const int* __restrict__ edge,
                                                 float* __restrict__ aggr) {
    int tid = blockIdx.x * 256 + threadIdx.x;
    int e = tid >> 5;
    int c = (tid & 31) << 2;
    int dst = edge[e];
    int src = edge[NE + e];
    const floatx4 v = *(const floatx4*)(x + src * HD + c);
    float* ap = aggr + dst * HD + c;
    unsafeAtomicAdd(ap + 0, v[0]);
    unsafeAtomicAdd(ap + 1, v[1]);
    unsafeAtomicAdd(ap + 2, v[2]);
    unsafeAtomicAdd(ap + 3, v[3]);
}

// ======== dedicated gather-aggregate: 4 nodes/wave, no LDS -> 16 waves/CU ========
// Serial chain per wave = ceil(max-of-4-degrees / 8) ~ 2 exposures (vs 5 in the fused kernel's
// max-of-16 layout); 8 uint4 loads in flight per lane; zero-row clamp removes the scalar tail.
// Writes aggr fully (deg-0 nodes write zeros) -> no pre-zeroing needed.
__global__ __launch_bounds__(256) void k_aggr(
    const bf16* __restrict__ xb, const int* __restrict__ cur,
    const int* __restrict__ bucket,
    const int* __restrict__ ovf_cnt, const int* __restrict__ ovf,
    float* __restrict__ aggr)
{
    const int gw   = (blockIdx.x * 256 + threadIdx.x) >> 6;   // wave id
    const int lane = threadIdx.x & 63;
    const int quad = lane >> 4;
    const int ln   = lane & 15;
    const int node = gw * 4 + quad;                           // 12500 waves x 4 = 50000 exact
    const int f8   = ln * 8;                                  // this lane's feature slice

    floatx4 a0 = {0.f, 0.f, 0.f, 0.f}, a1 = {0.f, 0.f, 0.f, 0.f};
    const int deg = cur[node];
    const int n   = (deg < CAP) ? deg : CAP;
    const int* bk = bucket + (size_t)node * CAP;

    int t = 0;
    while (t < n) {
        // index reads may extend past this node's live entries but stay inside the row (CAP=128)
        const int4 s0 = *(const int4*)(bk + t);
        const int4 s1 = *(const int4*)(bk + t + 4);
        const int i0 = s0.x;                          // t < n guaranteed
        const int i1 = (t + 1 < n) ? s0.y : NN;       // NN = zero row -> no-op add
        const int i2 = (t + 2 < n) ? s0.z : NN;
        const int i3 = (t + 3 < n) ? s0.w : NN;
        const int i4 = (t + 4 < n) ? s1.x : NN;
        const int i5 = (t + 5 < n) ? s1.y : NN;
        const int i6 = (t + 6 < n) ? s1.z : NN;
        const int i7 = (t + 7 < n) ? s1.w : NN;
        // issue all 8 loads straight-line, then unpack (max MLP)
        const uint4 v0 = *(const uint4*)(xb + (size_t)i0 * HD + f8);
        const uint4 v1 = *(const uint4*)(xb + (size_t)i1 * HD + f8);
        const uint4 v2 = *(const uint4*)(xb + (size_t)i2 * HD + f8);
        const uint4 v3 = *(const uint4*)(xb + (size_t)i3 * HD + f8);
        const uint4 v4 = *(const uint4*)(xb + (size_t)i4 * HD + f8);
        const uint4 v5 = *(const uint4*)(xb + (size_t)i5 * HD + f8);
        const uint4 v6 = *(const uint4*)(xb + (size_t)i6 * HD + f8);
        const uint4 v7 = *(const uint4*)(xb + (size_t)i7 * HD + f8);
        addrow(a0, a1, v0); addrow(a0, a1, v1);
        addrow(a0, a1, v2); addrow(a0, a1, v3);
        addrow(a0, a1, v4); addrow(a0, a1, v5);
        addrow(a0, a1, v6); addrow(a0, a1, v7);
        t += 8;
    }
    if (deg > CAP) {                  // never fires for the bench inputs
        const int m = *ovf_cnt;
        for (int i = 0; i < m; i++) {
            if (ovf[2 * i] == node) {
                const uint4 v = *(const uint4*)(xb + (size_t)ovf[2 * i + 1] * HD + f8);
                addrow(a0, a1, v);
            }
        }
    }
    *(floatx4*)(aggr + (size_t)node * HD + f8)     = a0;   // coalesced: 512B/quad
    *(floatx4*)(aggr + (size_t)node * HD + f8 + 4) = a1;
}

// ======== GEMM1 + GEMM2 with LDS overlay (~70.7 KB -> 2 blocks/CU) ========
// Aggregation is complete in aggr; this kernel preloads ag (8 loads) + ax (4 loads) per lane
// BEFORE __syncthreads so they ride under the LDS weight staging.
__global__ __launch_bounds__(256) void k_gemm12(
    const float* __restrict__ aggr, const float* __restrict__ x, const bf16* __restrict__ xb,
    int tier,
    const bf16* __restrict__ wlb, const bf16* __restrict__ w01b, const bf16* __restrict__ owb,
    const float* __restrict__ bias1, const float* __restrict__ bias2,
    float* __restrict__ out)
{
    __shared__ bf16 sA[128 * 136];        // wl, then ow
    __shared__ bf16 sB[128 * 136];        // w01, then tp (h transpose)
    __shared__ float b1_s[128], b2_s[128];
    float* tp = (float*)sB;               // [4][16][132]
    const int tid = threadIdx.x;

#pragma unroll
    for (int it = 0; it < 8; it++) {
        int i = tid + it * 256;
        int r = i >> 4;
        int o = (i & 15) << 3;
        *(bf16x8*)(sA + r * 136 + o) = *(const bf16x8*)(wlb  + r * 128 + o);
        *(bf16x8*)(sB + r * 136 + o) = *(const bf16x8*)(w01b + r * 128 + o);
    }
    if (tid < 128) { b1_s[tid] = bias1[tid]; b2_s[tid] = bias2[tid]; }

    const int lane = tid & 63;
    const int wv   = tid >> 6;
    const int ln   = lane & 15;
    const int quad = lane >> 4;
    const int row0 = blockIdx.x * 64 + wv * 16;
    const int arow = row0 + ln;
    const bool aok = arow < NN;
    const int q8   = quad * 8;

    floatx4 ag0[4] = {};
    floatx4 ag1[4] = {};
    bf16x8 ax[4] = {zero8(), zero8(), zero8(), zero8()};
    if (aok) {
#pragma unroll
        for (int kc = 0; kc < 4; kc++) {
            ag0[kc] = *(const floatx4*)(aggr + (size_t)arow * HD + kc * 32 + q8);
            ag1[kc] = *(const floatx4*)(aggr + (size_t)arow * HD + kc * 32 + q8 + 4);
        }
        if (tier) {
#pragma unroll
            for (int kc = 0; kc < 4; kc++)
                ax[kc] = *(const bf16x8*)(xb + (size_t)arow * HD + kc * 32 + q8);
        } else {
#pragma unroll
            for (int kc = 0; kc < 4; kc++) {
                const floatx4 g0 = *(const floatx4*)(x + (size_t)arow * HD + kc * 32 + q8);
                const floatx4 g1 = *(const floatx4*)(x + (size_t)arow * HD + kc * 32 + q8 + 4);
                ax[kc] = cvt8(g0, g1);
            }
        }
    }

    __syncthreads();                      // weights staged; operands live in regs

    floatx4 acc[8] = {};

    // ---- GEMM1 ----
#pragma unroll
    for (int kc = 0; kc < 4; kc++) {
        const int k0 = kc * 32 + q8;
        bf16x8 a_hi, a_lo;
        split8(ag0[kc], ag1[kc], a_hi, a_lo);
#pragma unroll
        for (int nc = 0; nc < 8; nc++) {
            const bf16x8 bw  = *(const bf16x8*)(sA + (nc * 16 + ln) * 136 + k0);
            const bf16x8 bw2 = *(const bf16x8*)(sB + (nc * 16 + ln) * 136 + k0);
            acc[nc] = __builtin_amdgcn_mfma_f32_16x16x32_bf16(a_hi,  bw,  acc[nc], 0, 0, 0);
            acc[nc] = __builtin_amdgcn_mfma_f32_16x16x32_bf16(a_lo,  bw,  acc[nc], 0, 0, 0);
            acc[nc] = __builtin_amdgcn_mfma_f32_16x16x32_bf16(ax[kc], bw2, acc[nc], 0, 0, 0);
        }
    }
    __syncthreads();

    // ---- overlay: restage ow into sA; park relu(h) into tp (over sB) ----
#pragma unroll
    for (int it = 0; it < 8; it++) {
        int i = tid + it * 256;
        int r = i >> 4;
        int o = (i & 15) << 3;
        *(bf16x8*)(sA + r * 136 + o) = *(const bf16x8*)(owb + r * 128 + o);
    }
#pragma unroll
    for (int nc = 0; nc < 8; nc++) {
        const int col = nc * 16 + ln;
        const float bv = b1_s[col];
#pragma unroll
        for (int r = 0; r < 4; r++) {
            float v = acc[nc][r] + bv;
            tp[wv * 2112 + (quad * 4 + r) * 132 + col] = (v > 0.f ? v : 0.f);
        }
        acc[nc][0] = acc[nc][1] = acc[nc][2] = acc[nc][3] = 0.f;
    }
    __syncthreads();

    // ---- GEMM2 ----
#pragma unroll
    for (int kc = 0; kc < 4; kc++) {
        const int k0 = kc * 32 + q8;
        const floatx4 f0 = *(const floatx4*)(tp + wv * 2112 + ln * 132 + k0);
        const floatx4 f1 = *(const floatx4*)(tp + wv * 2112 + ln * 132 + k0 + 4);
        bf16x8 a_hi, a_lo;
        split8(f0, f1, a_hi, a_lo);
#pragma unroll
        for (int nc = 0; nc < 8; nc++) {
            const bf16x8 bw = *(const bf16x8*)(sA + (nc * 16 + ln) * 136 + k0);
            acc[nc] = __builtin_amdgcn_mfma_f32_16x16x32_bf16(a_hi, bw, acc[nc], 0, 0, 0);
            acc[nc] = __builtin_amdgcn_mfma_f32_16x16x32_bf16(a_lo, bw, acc[nc], 0, 0, 0);
        }
    }

#pragma unroll
    for (int nc = 0; nc < 8; nc++) {
        const int col = nc * 16 + ln;
        const float bv = b2_s[col];
#pragma unroll
        for (int r = 0; r < 4; r++) {
            const int row = row0 + quad * 4 + r;
            if (row < NN) out[row * 128 + col] = acc[nc][r] + bv;
        }
    }
}

extern "C" void kernel_launch(void* const* d_in, const int* in_sizes, int n_in,
                              void* d_out, int out_size, void* d_ws, size_t ws_size,
                              hipStream_t stream) {
    const float* x_a     = (const float*)d_in[0];
    const int*   edge_ba = (const int*)d_in[3];
    const float* c1_w0_w = (const float*)d_in[10];
    const float* c1_w0_b = (const float*)d_in[11];
    const float* c1_wl_w = (const float*)d_in[12];
    const float* c1_wl_b = (const float*)d_in[13];
    const float* c1_w1_w = (const float*)d_in[14];
    const float* c1_w1_b = (const float*)d_in[15];
    const float* out_w   = (const float*)d_in[16];
    const float* out_b   = (const float*)d_in[17];

    char* p = (char*)d_ws;
    float* aggr  = (float*)p;   p += (size_t)NN * HD * 4;     // 25.6 MB
    bf16*  wlb   = (bf16*)p;    p += 32768;
    bf16*  w01b  = (bf16*)p;    p += 32768;
    bf16*  owb   = (bf16*)p;    p += 32768;
    float* bias1 = (float*)p;   p += 512;
    float* bias2 = (float*)p;   p += 512;
    const size_t WS_FALL = (size_t)(p - (char*)d_ws);         // ~25.7 MB
    int*   cur    = (int*)p;    p += 200704;                  // NN ints (padded)
    int*   bucket = (int*)p;    p += (size_t)NN * CAP * 4;    // 25.6 MB
    bf16*  xb     = (bf16*)p;   p += (size_t)(NN + 2) * HD * 2; // 12.8 MB + zero row NN
    int*   ovf_cnt= (int*)p;    p += 256;
    int*   ovf    = (int*)p;    p += (size_t)NE * 2 * 4;      // 4 MB overflow (dst,src) pairs
    const size_t WS_BUCKET = (size_t)(p - (char*)d_ws);       // ~68.5 MB (ws = 256 MiB)
    (void)WS_FALL;

    const int tier = (ws_size >= WS_BUCKET) ? 1 : 0;

    const int k1_grid = tier ? (PREP_B + ZCUR_B) : (PREP_B + ZCUR_B + ZAGGR_B);
    k_setup1<<<k1_grid, 256, 0, stream>>>(c1_wl_w, c1_w0_w, c1_w1_w,
                                          c1_wl_b, c1_w0_b, c1_w1_b,
                                          out_w, out_b,
                                          wlb, w01b, owb, bias1, bias2,
                                          aggr, cur, ovf_cnt, xb, tier);

    if (tier) {
        k_setup2<<<K2_B, 256, 0, stream>>>(edge_ba, x_a, cur, bucket, ovf_cnt, ovf, xb);
        k_aggr  <<<3125, 256, 0, stream>>>(xb, cur, bucket, ovf_cnt, ovf, aggr);
    } else {
        k_scatter<<<NE * 32 / 256, 256, 0, stream>>>(x_a, edge_ba, aggr);
    }

    k_gemm12<<<(NN + 63) / 64, 256, 0, stream>>>(aggr, x_a, xb, tier,
                                                 wlb, w01b, owb, bias1, bias2,
                                                 (float*)d_out);
}

// Round 11
// 190.086 us; speedup vs baseline: 1.3694x; 1.0135x over previous
//
#include <hip/hip_runtime.h>
#include <hip/hip_bf16.h>

#define NN 50000
#define NE 500000
#define HD 128
#define CAP 128
#define PREP_B 24
#define ZCUR_B ((NN + 255) / 256)          // 196
#define ZAGGR_B 6250
#define XCONV_B 3125
#define FILL4_B ((NE / 4 + 255) / 256)     // 489 (bucket fill, 4 edges/thread)

typedef __bf16 bf16;
typedef __attribute__((ext_vector_type(8))) __bf16 bf16x8;
typedef __attribute__((ext_vector_type(4))) float floatx4;

__device__ inline float u2f(unsigned int lo16) {
    union { unsigned int i; float f; } c; c.i = lo16 << 16; return c.f;
}

__device__ inline bf16x8 cvt8(floatx4 a, floatx4 b) {
    bf16x8 r;
#pragma unroll
    for (int j = 0; j < 4; j++) { r[j] = (bf16)a[j]; r[j + 4] = (bf16)b[j]; }
    return r;
}

__device__ inline void split8(const floatx4 f0, const floatx4 f1, bf16x8& hi, bf16x8& lo) {
#pragma unroll
    for (int j = 0; j < 4; j++) {
        float a = f0[j]; bf16 h = (bf16)a; hi[j] = h; lo[j] = (bf16)(a - (float)h);
        float b = f1[j]; bf16 g = (bf16)b; hi[j + 4] = g; lo[j + 4] = (bf16)(b - (float)g);
    }
}

__device__ inline bf16x8 zero8() {
    bf16x8 v;
#pragma unroll
    for (int j = 0; j < 8; j++) v[j] = (bf16)0.f;
    return v;
}

// accumulate 8 bf16 (one uint4) into two floatx4
__device__ inline void addrow(floatx4& f0, floatx4& f1, const uint4 v) {
    f0[0] += u2f(v.x & 0xffff); f0[1] += u2f(v.x >> 16);
    f0[2] += u2f(v.y & 0xffff); f0[3] += u2f(v.y >> 16);
    f1[0] += u2f(v.z & 0xffff); f1[1] += u2f(v.z >> 16);
    f1[2] += u2f(v.w & 0xffff); f1[3] += u2f(v.w >> 16);
}

// ===== K1: weights->bf16 (24) | zero cur + ovf + xb zero-row (196) |
//           tier1: x->bf16 (3125)  /  tier0: zero aggr (6250) =====
// x->bf16 depends only on input x, so it moves here from K2 (K2 was latency-bound at 40.6us
// with conversion co-scheduled; K1 was 220 blocks / ~2us, under-utilizing the chip).
__global__ __launch_bounds__(256) void k_setup1(
    const float* __restrict__ wl, const float* __restrict__ w0, const float* __restrict__ w1,
    const float* __restrict__ bl, const float* __restrict__ b0, const float* __restrict__ b1,
    const float* __restrict__ ow, const float* __restrict__ ob,
    const float* __restrict__ x,
    bf16* __restrict__ wlb, bf16* __restrict__ w01b, bf16* __restrict__ owb,
    float* __restrict__ bias1, float* __restrict__ bias2,
    float* __restrict__ aggr, int* __restrict__ cur, int* __restrict__ ovf_cnt,
    bf16* __restrict__ xb, int tier)
{
    const int b = blockIdx.x, tid = threadIdx.x;
    if (b < PREP_B) {
        int g = b * 256 + tid;
        int m = g >> 11, off = (g & 2047) << 3;
        if (m == 0) {
            const floatx4 a = *(const floatx4*)(wl + off);
            const floatx4 c = *(const floatx4*)(wl + off + 4);
            *(bf16x8*)(wlb + off) = cvt8(a, c);
        } else if (m == 1) {
            floatx4 a = *(const floatx4*)(w0 + off);
            floatx4 c = *(const floatx4*)(w0 + off + 4);
            const floatx4 d = *(const floatx4*)(w1 + off);
            const floatx4 e = *(const floatx4*)(w1 + off + 4);
#pragma unroll
            for (int j = 0; j < 4; j++) { a[j] += d[j]; c[j] += e[j]; }
            *(bf16x8*)(w01b + off) = cvt8(a, c);
        } else {
            const floatx4 a = *(const floatx4*)(ow + off);
            const floatx4 c = *(const floatx4*)(ow + off + 4);
            *(bf16x8*)(owb + off) = cvt8(a, c);
        }
        if (g < 128) bias1[g] = bl[g] + b0[g] + b1[g];
        else if (g < 256) bias2[g - 128] = ob[g - 128];
    } else if (b < PREP_B + ZCUR_B) {
        if (tier >= 1) {
            int i = (b - PREP_B) * 256 + tid;
            if (i < NN) cur[i] = 0;
            else if (i < NN + 16) *(bf16x8*)(xb + (size_t)NN * HD + (i - NN) * 8) = zero8();
            if (b == PREP_B && tid == 0) *ovf_cnt = 0;
        }
    } else {
        int c = b - PREP_B - ZCUR_B;
        if (tier >= 1) {                  // x -> bf16 (3125 blocks)
            int off = (c * 256 + tid) << 3;
            const floatx4 a = *(const floatx4*)(x + off);
            const floatx4 d = *(const floatx4*)(x + off + 4);
            *(bf16x8*)(xb + off) = cvt8(a, d);
        } else {                          // tier-0: zero aggr (6250 blocks)
            int i = c * 256 + tid;
            floatx4 z = {0.f, 0.f, 0.f, 0.f};
            ((floatx4*)aggr)[i] = z;
        }
    }
}

// ===== K2: bucket append ONLY, 4 edges/thread =====
// k_setup2 was the 2nd-largest kernel (40.6us) with VALUBusy 0.7% — pure atomic-latency-bound,
// one serialized chain per lane. 4 independent atomicAdd chains per lane -> 4x MLP.
__global__ __launch_bounds__(256) void k_setup2(
    const int* __restrict__ edge,
    int* __restrict__ cur, int* __restrict__ bucket,
    int* __restrict__ ovf_cnt, int* __restrict__ ovf)
{
    const int g = blockIdx.x * 256 + threadIdx.x;
    const int e0 = g * 4;
    if (e0 >= NE) return;                         // NE % 4 == 0: full int4 always valid
    const int4 d = *(const int4*)(edge + e0);
    const int4 s = *(const int4*)(edge + NE + e0);
    // 4 independent atomics issued back-to-back (all in flight together)
    const int p0 = atomicAdd(&cur[d.x], 1);
    const int p1 = atomicAdd(&cur[d.y], 1);
    const int p2 = atomicAdd(&cur[d.z], 1);
    const int p3 = atomicAdd(&cur[d.w], 1);
    if (p0 < CAP) bucket[d.x * CAP + p0] = s.x;
    else { int oi = atomicAdd(ovf_cnt, 1); ovf[2 * oi] = d.x; ovf[2 * oi + 1] = s.x; }
    if (p1 < CAP) bucket[d.y * CAP + p1] = s.y;
    else { int oi = atomicAdd(ovf_cnt, 1); ovf[2 * oi] = d.y; ovf[2 * oi + 1] = s.y; }
    if (p2 < CAP) bucket[d.z * CAP + p2] = s.z;
    else { int oi = atomicAdd(ovf_cnt, 1); ovf[2 * oi] = d.z; ovf[2 * oi + 1] = s.z; }
    if (p3 < CAP) bucket[d.w * CAP + p3] = s.w;
    else { int oi = atomicAdd(ovf_cnt, 1); ovf[2 * oi] = d.w; ovf[2 * oi + 1] = s.w; }
}

// ======== fallback atomic scatter (tier-0, proven; aggr pre-zeroed by K1) ========
__global__ __launch_bounds__(256) void k_scatter(const float* __restrict__ x,
                                                 const int* __restrict__ edge,
                                                 float* __restrict__ aggr) {
    int tid = blockIdx.x * 256 + threadIdx.x;
    int e = tid >> 5;
    int c = (tid & 31) << 2;
    int dst = edge[e];
    int src = edge[NE + e];
    const floatx4 v = *(const floatx4*)(x + src * HD + c);
    float* ap = aggr + dst * HD + c;
    unsafeAtomicAdd(ap + 0, v[0]);
    unsafeAtomicAdd(ap + 1, v[1]);
    unsafeAtomicAdd(ap + 2, v[2]);
    unsafeAtomicAdd(ap + 3, v[3]);
}

// ======== dedicated gather-aggregate: 4 nodes/wave, no LDS -> 16 waves/CU ========
// Fabric-BW-bound (~4.3 TB/s random 64B reads from L3) — measured equal to the fused variant;
// kept split for profile visibility and the higher-occupancy structure.
__global__ __launch_bounds__(256) void k_aggr(
    const bf16* __restrict__ xb, const int* __restrict__ cur,
    const int* __restrict__ bucket,
    const int* __restrict__ ovf_cnt, const int* __restrict__ ovf,
    float* __restrict__ aggr)
{
    const int gw   = (blockIdx.x * 256 + threadIdx.x) >> 6;   // wave id
    const int lane = threadIdx.x & 63;
    const int quad = lane >> 4;
    const int ln   = lane & 15;
    const int node = gw * 4 + quad;                           // 12500 waves x 4 = 50000 exact
    const int f8   = ln * 8;                                  // this lane's feature slice

    floatx4 a0 = {0.f, 0.f, 0.f, 0.f}, a1 = {0.f, 0.f, 0.f, 0.f};
    const int deg = cur[node];
    const int n   = (deg < CAP) ? deg : CAP;
    const int* bk = bucket + (size_t)node * CAP;

    int t = 0;
    while (t < n) {
        // index reads may extend past this node's live entries but stay inside the row (CAP=128)
        const int4 s0 = *(const int4*)(bk + t);
        const int4 s1 = *(const int4*)(bk + t + 4);
        const int i0 = s0.x;                          // t < n guaranteed
        const int i1 = (t + 1 < n) ? s0.y : NN;       // NN = zero row -> no-op add
        const int i2 = (t + 2 < n) ? s0.z : NN;
        const int i3 = (t + 3 < n) ? s0.w : NN;
        const int i4 = (t + 4 < n) ? s1.x : NN;
        const int i5 = (t + 5 < n) ? s1.y : NN;
        const int i6 = (t + 6 < n) ? s1.z : NN;
        const int i7 = (t + 7 < n) ? s1.w : NN;
        // issue all 8 loads straight-line, then unpack (max MLP)
        const uint4 v0 = *(const uint4*)(xb + (size_t)i0 * HD + f8);
        const uint4 v1 = *(const uint4*)(xb + (size_t)i1 * HD + f8);
        const uint4 v2 = *(const uint4*)(xb + (size_t)i2 * HD + f8);
        const uint4 v3 = *(const uint4*)(xb + (size_t)i3 * HD + f8);
        const uint4 v4 = *(const uint4*)(xb + (size_t)i4 * HD + f8);
        const uint4 v5 = *(const uint4*)(xb + (size_t)i5 * HD + f8);
        const uint4 v6 = *(const uint4*)(xb + (size_t)i6 * HD + f8);
        const uint4 v7 = *(const uint4*)(xb + (size_t)i7 * HD + f8);
        addrow(a0, a1, v0); addrow(a0, a1, v1);
        addrow(a0, a1, v2); addrow(a0, a1, v3);
        addrow(a0, a1, v4); addrow(a0, a1, v5);
        addrow(a0, a1, v6); addrow(a0, a1, v7);
        t += 8;
    }
    if (deg > CAP) {                  // never fires for the bench inputs
        const int m = *ovf_cnt;
        for (int i = 0; i < m; i++) {
            if (ovf[2 * i] == node) {
                const uint4 v = *(const uint4*)(xb + (size_t)ovf[2 * i + 1] * HD + f8);
                addrow(a0, a1, v);
            }
        }
    }
    *(floatx4*)(aggr + (size_t)node * HD + f8)     = a0;   // coalesced: 512B/quad
    *(floatx4*)(aggr + (size_t)node * HD + f8 + 4) = a1;
}

// ======== GEMM1 + GEMM2 with LDS overlay (~70.7 KB -> 2 blocks/CU) ========
// Preloads ag (8 loads) + ax (4 loads) per lane BEFORE __syncthreads so they ride
// under the LDS weight staging.
__global__ __launch_bounds__(256) void k_gemm12(
    const float* __restrict__ aggr, const float* __restrict__ x, const bf16* __restrict__ xb,
    int tier,
    const bf16* __restrict__ wlb, const bf16* __restrict__ w01b, const bf16* __restrict__ owb,
    const float* __restrict__ bias1, const float* __restrict__ bias2,
    float* __restrict__ out)
{
    __shared__ bf16 sA[128 * 136];        // wl, then ow
    __shared__ bf16 sB[128 * 136];        // w01, then tp (h transpose)
    __shared__ float b1_s[128], b2_s[128];
    float* tp = (float*)sB;               // [4][16][132]
    const int tid = threadIdx.x;

#pragma unroll
    for (int it = 0; it < 8; it++) {
        int i = tid + it * 256;
        int r = i >> 4;
        int o = (i & 15) << 3;
        *(bf16x8*)(sA + r * 136 + o) = *(const bf16x8*)(wlb  + r * 128 + o);
        *(bf16x8*)(sB + r * 136 + o) = *(const bf16x8*)(w01b + r * 128 + o);
    }
    if (tid < 128) { b1_s[tid] = bias1[tid]; b2_s[tid] = bias2[tid]; }

    const int lane = tid & 63;
    const int wv   = tid >> 6;
    const int ln   = lane & 15;
    const int quad = lane >> 4;
    const int row0 = blockIdx.x * 64 + wv * 16;
    const int arow = row0 + ln;
    const bool aok = arow < NN;
    const int q8   = quad * 8;

    floatx4 ag0[4] = {};
    floatx4 ag1[4] = {};
    bf16x8 ax[4] = {zero8(), zero8(), zero8(), zero8()};
    if (aok) {
#pragma unroll
        for (int kc = 0; kc < 4; kc++) {
            ag0[kc] = *(const floatx4*)(aggr + (size_t)arow * HD + kc * 32 + q8);
            ag1[kc] = *(const floatx4*)(aggr + (size_t)arow * HD + kc * 32 + q8 + 4);
        }
        if (tier) {
#pragma unroll
            for (int kc = 0; kc < 4; kc++)
                ax[kc] = *(const bf16x8*)(xb + (size_t)arow * HD + kc * 32 + q8);
        } else {
#pragma unroll
            for (int kc = 0; kc < 4; kc++) {
                const floatx4 g0 = *(const floatx4*)(x + (size_t)arow * HD + kc * 32 + q8);
                const floatx4 g1 = *(const floatx4*)(x + (size_t)arow * HD + kc * 32 + q8 + 4);
                ax[kc] = cvt8(g0, g1);
            }
        }
    }

    __syncthreads();                      // weights staged; operands live in regs

    floatx4 acc[8] = {};

    // ---- GEMM1 ----
#pragma unroll
    for (int kc = 0; kc < 4; kc++) {
        const int k0 = kc * 32 + q8;
        bf16x8 a_hi, a_lo;
        split8(ag0[kc], ag1[kc], a_hi, a_lo);
#pragma unroll
        for (int nc = 0; nc < 8; nc++) {
            const bf16x8 bw  = *(const bf16x8*)(sA + (nc * 16 + ln) * 136 + k0);
            const bf16x8 bw2 = *(const bf16x8*)(sB + (nc * 16 + ln) * 136 + k0);
            acc[nc] = __builtin_amdgcn_mfma_f32_16x16x32_bf16(a_hi,  bw,  acc[nc], 0, 0, 0);
            acc[nc] = __builtin_amdgcn_mfma_f32_16x16x32_bf16(a_lo,  bw,  acc[nc], 0, 0, 0);
            acc[nc] = __builtin_amdgcn_mfma_f32_16x16x32_bf16(ax[kc], bw2, acc[nc], 0, 0, 0);
        }
    }
    __syncthreads();

    // ---- overlay: restage ow into sA; park relu(h) into tp (over sB) ----
#pragma unroll
    for (int it = 0; it < 8; it++) {
        int i = tid + it * 256;
        int r = i >> 4;
        int o = (i & 15) << 3;
        *(bf16x8*)(sA + r * 136 + o) = *(const bf16x8*)(owb + r * 128 + o);
    }
#pragma unroll
    for (int nc = 0; nc < 8; nc++) {
        const int col = nc * 16 + ln;
        const float bv = b1_s[col];
#pragma unroll
        for (int r = 0; r < 4; r++) {
            float v = acc[nc][r] + bv;
            tp[wv * 2112 + (quad * 4 + r) * 132 + col] = (v > 0.f ? v : 0.f);
        }
        acc[nc][0] = acc[nc][1] = acc[nc][2] = acc[nc][3] = 0.f;
    }
    __syncthreads();

    // ---- GEMM2 ----
#pragma unroll
    for (int kc = 0; kc < 4; kc++) {
        const int k0 = kc * 32 + q8;
        const floatx4 f0 = *(const floatx4*)(tp + wv * 2112 + ln * 132 + k0);
        const floatx4 f1 = *(const floatx4*)(tp + wv * 2112 + ln * 132 + k0 + 4);
        bf16x8 a_hi, a_lo;
        split8(f0, f1, a_hi, a_lo);
#pragma unroll
        for (int nc = 0; nc < 8; nc++) {
            const bf16x8 bw = *(const bf16x8*)(sA + (nc * 16 + ln) * 136 + k0);
            acc[nc] = __builtin_amdgcn_mfma_f32_16x16x32_bf16(a_hi, bw, acc[nc], 0, 0, 0);
            acc[nc] = __builtin_amdgcn_mfma_f32_16x16x32_bf16(a_lo, bw, acc[nc], 0, 0, 0);
        }
    }

#pragma unroll
    for (int nc = 0; nc < 8; nc++) {
        const int col = nc * 16 + ln;
        const float bv = b2_s[col];
#pragma unroll
        for (int r = 0; r < 4; r++) {
            const int row = row0 + quad * 4 + r;
            if (row < NN) out[row * 128 + col] = acc[nc][r] + bv;
        }
    }
}

extern "C" void kernel_launch(void* const* d_in, const int* in_sizes, int n_in,
                              void* d_out, int out_size, void* d_ws, size_t ws_size,
                              hipStream_t stream) {
    const float* x_a     = (const float*)d_in[0];
    const int*   edge_ba = (const int*)d_in[3];
    const float* c1_w0_w = (const float*)d_in[10];
    const float* c1_w0_b = (const float*)d_in[11];
    const float* c1_wl_w = (const float*)d_in[12];
    const float* c1_wl_b = (const float*)d_in[13];
    const float* c1_w1_w = (const float*)d_in[14];
    const float* c1_w1_b = (const float*)d_in[15];
    const float* out_w   = (const float*)d_in[16];
    const float* out_b   = (const float*)d_in[17];

    char* p = (char*)d_ws;
    float* aggr  = (float*)p;   p += (size_t)NN * HD * 4;     // 25.6 MB
    bf16*  wlb   = (bf16*)p;    p += 32768;
    bf16*  w01b  = (bf16*)p;    p += 32768;
    bf16*  owb   = (bf16*)p;    p += 32768;
    float* bias1 = (float*)p;   p += 512;
    float* bias2 = (float*)p;   p += 512;
    const size_t WS_FALL = (size_t)(p - (char*)d_ws);         // ~25.7 MB
    int*   cur    = (int*)p;    p += 200704;                  // NN ints (padded)
    int*   bucket = (int*)p;    p += (size_t)NN * CAP * 4;    // 25.6 MB
    bf16*  xb     = (bf16*)p;   p += (size_t)(NN + 2) * HD * 2; // 12.8 MB + zero row NN
    int*   ovf_cnt= (int*)p;    p += 256;
    int*   ovf    = (int*)p;    p += (size_t)NE * 2 * 4;      // 4 MB overflow (dst,src) pairs
    const size_t WS_BUCKET = (size_t)(p - (char*)d_ws);       // ~68.5 MB (ws = 256 MiB)
    (void)WS_FALL;

    const int tier = (ws_size >= WS_BUCKET) ? 1 : 0;

    const int k1_grid = tier ? (PREP_B + ZCUR_B + XCONV_B) : (PREP_B + ZCUR_B + ZAGGR_B);
    k_setup1<<<k1_grid, 256, 0, stream>>>(c1_wl_w, c1_w0_w, c1_w1_w,
                                          c1_wl_b, c1_w0_b, c1_w1_b,
                                          out_w, out_b, x_a,
                                          wlb, w01b, owb, bias1, bias2,
                                          aggr, cur, ovf_cnt, xb, tier);

    if (tier) {
        k_setup2<<<FILL4_B, 256, 0, stream>>>(edge_ba, cur, bucket, ovf_cnt, ovf);
        k_aggr  <<<3125, 256, 0, stream>>>(xb, cur, bucket, ovf_cnt, ovf, aggr);
    } else {
        k_scatter<<<NE * 32 / 256, 256, 0, stream>>>(x_a, edge_ba, aggr);
    }

    k_gemm12<<<(NN + 63) / 64, 256, 0, stream>>>(aggr, x_a, xb, tier,
                                                 wlb, w01b, owb, bias1, bias2,
                                                 (float*)d_out);
}